// Round 7
// baseline (20855.537 us; speedup 1.0000x reference)
//
#include <hip/hip_runtime.h>
#include <hip/hip_fp16.h>
#include <cstdint>
#include <cstddef>

typedef _Float16 f16;
typedef _Float16 f16x8 __attribute__((ext_vector_type(8)));
typedef _Float16 f16x4 __attribute__((ext_vector_type(4)));
typedef float    f32x4 __attribute__((ext_vector_type(4)));

// ---------------- ws layout (bytes) ----------------
// Gs   f32 [2048][10]                :      0 ..  81920
// QM   f32 [10][16]                  :  81920 ..  82560
// CB   f32 [10][16]                  :  82560 ..  83200
// W1T  f16 [16][5][4][80]            :  83200 .. 134400   (dead after k1)
//   A9  f16 [57][64][4]  (overlay)   :  83200 .. 112384   (written after k1)
// WhhP f16 [57*10][64][8]            : 134400 .. 718080
// giP  f16 [2048][57][64][4]         : 718080 .. 60486912
#define WS_GS    0u
#define WS_QM    81920u
#define WS_CB    82560u
#define WS_W1T   83200u
#define WS_A9    83200u
#define WS_WHHP  134400u
#define WS_GIP   718080u

__device__ __forceinline__ float sigm_(float x){ return 1.0f/(1.0f + __expf(-x)); }
__device__ __forceinline__ float tanh_(float x){
  float ax = fabsf(x);
  float e  = __expf(-2.0f*ax);
  float r  = (1.0f - e)/(1.0f + e);
  return x < 0.0f ? -r : r;
}
__device__ __forceinline__ int imin_(int a,int b){ return a<b?a:b; }

// ================= K0: prep (QM, CB, W1T) =================
__global__ __launch_bounds__(512) void k0_prep(
    const float* __restrict__ q, const float* __restrict__ m,
    const float* __restrict__ W1, const float* __restrict__ b1,
    float* __restrict__ QM, float* __restrict__ CBo, f16* __restrict__ W1T)
{
  int tid = threadIdx.x;
  if (tid < 160){
    int k = tid >> 4, h = tid & 15;
    float acc = 0.f;
    for (int d = 0; d < 300; ++d)
      acc += q[k*300+d]*W1[(2100+d)*16+h] + m[k*300+d]*W1[(2400+d)*16+h];
    QM[tid] = acc;
  } else if (tid < 320){
    int b = (tid-160) >> 4, h = tid & 15;
    float acc = b1[h];
    for (int d = 0; d < 300; ++d)
      acc += m[b*300+d]*W1[(300+d)*16+h] + q[b*300+d]*W1[(600+d)*16+h];
    CBo[tid-160] = acc;
  }
  const int blkoff[5] = {0, 900, 1200, 1500, 1800};
  for (int i = tid; i < 25600; i += 512){
    int ii = i % 80; int r = i / 80;
    int dg = r % 4; r /= 4;
    int blk = r % 5; int h = r / 5;
    int d = dg*80 + ii;
    float v = 0.f;
    if (d < 300) v = W1[(blkoff[blk]+d)*16 + h];
    W1T[i] = (f16)v;
  }
}

// ================= Kpack: Whh -> MFMA A-fragment layout (f16) =================
__global__ __launch_bounds__(64) void k_pack(const float* __restrict__ Whh, f16* __restrict__ WhhP)
{
  int bid = blockIdx.x, l = threadIdx.x;
  int mt = bid / 10, kc = bid % 10;
  int gate = mt / 19, cb = mt % 19;
  int rr = l & 15, grp = l >> 4;
  int c = cb*16 + rr;
  int j = gate*300 + imin_(c, 299);
  f16x8 v;
  #pragma unroll
  for (int e = 0; e < 8; ++e){
    int d = kc*32 + grp*8 + e;
    float x = Whh[(size_t)imin_(d,299)*900 + j];
    v[e] = (f16)((d < 300 && c < 300) ? x : 0.f);
  }
  *(f16x8*)&WhhP[((size_t)bid*64 + l)*8] = v;
}

// ================= Kpack9: kc9 as K=16 A-frag, with bhh_n bias row at k-slot 300 =================
__global__ __launch_bounds__(64) void k_pack9(const float* __restrict__ Whh,
                                              const float* __restrict__ bhh,
                                              f16* __restrict__ A9)
{
  int mt = blockIdx.x, l = threadIdx.x;
  int gate = mt / 19, cb = mt % 19;
  int row = l & 15, grp = l >> 4;
  int c = cb*16 + row;
  f16x4 v;
  #pragma unroll
  for (int e = 0; e < 4; ++e){
    int d = 288 + grp*4 + e;
    float x = 0.f;
    if (c < 300){
      if (d < 300) x = Whh[(size_t)d*900 + gate*300 + c];
      else if (d == 300 && gate == 2) x = bhh[600 + c];
    }
    v[e] = (f16)x;
  }
  *(f16x4*)&A9[((size_t)mt*64 + l)*4] = v;
}

// ================= K1: attention gate -> G[b][t] (d_out[0:20480]) =================
__global__ __launch_bounds__(512) void k1_attn(
    const float* __restrict__ cs, const float* __restrict__ mI, const float* __restrict__ qI,
    const float* __restrict__ mask, const float* __restrict__ Wb,
    const float* __restrict__ W2, const float* __restrict__ b2,
    const float* __restrict__ QMg, const float* __restrict__ CBg, const f16* __restrict__ W1Tg,
    float* __restrict__ Gout)
{
  __shared__ __align__(16) float q_s[3000];
  __shared__ __align__(16) float m_s[3000];
  __shared__ float Wb_s[3000];
  __shared__ float QM_s[160], CB_s[160], W2_s[16];
  __shared__ __align__(16) f16 W1T_s[25600];
  __shared__ float cwb_s[8][10][10];
  int tid = threadIdx.x;
  for (int i = tid; i < 3000; i += 512){ q_s[i] = qI[i]; m_s[i] = mI[i]; Wb_s[i] = Wb[i]; }
  for (int i = tid; i < 160; i += 512){ QM_s[i] = QMg[i]; CB_s[i] = CBg[i]; }
  if (tid < 16) W2_s[tid] = W2[tid];
  for (int i = tid; i < 25600; i += 512) W1T_s[i] = W1Tg[i];
  __syncthreads();

  int w = tid >> 6, l = tid & 63, dg = l >> 4, lo = l & 15;
  int t = blockIdx.x*8 + w;
  float a[10], cwb[10];
  #pragma unroll
  for (int b = 0; b < 10; ++b){ a[b] = 0.f; cwb[b] = 0.f; }

  for (int i = 0; i < 10; ++i){
    int d0 = dg*80 + i*8;
    const int wbase = lo*1600 + dg*80 + i*8;
    f16x8 wf0 = *(const f16x8*)&W1T_s[wbase + 0*320];
    f16x8 wf1 = *(const f16x8*)&W1T_s[wbase + 1*320];
    f16x8 wf2 = *(const f16x8*)&W1T_s[wbase + 2*320];
    f16x8 wf3 = *(const f16x8*)&W1T_s[wbase + 3*320];
    f16x8 wf4 = *(const f16x8*)&W1T_s[wbase + 4*320];
    int dc0 = imin_(d0, 296), dc1 = imin_(d0 + 4, 296);
    #pragma unroll
    for (int b = 0; b < 10; ++b){
      const float* csb = cs + ((size_t)t*10 + b)*300;
      float4 c0 = *(const float4*)(csb + dc0);
      float4 c1 = *(const float4*)(csb + dc1);
      float4 q0 = *(const float4*)(q_s + b*300 + dc0);
      float4 q1 = *(const float4*)(q_s + b*300 + dc1);
      float4 m0 = *(const float4*)(m_s + b*300 + dc0);
      float4 m1 = *(const float4*)(m_s + b*300 + dc1);
      float cv[8] = {c0.x,c0.y,c0.z,c0.w,c1.x,c1.y,c1.z,c1.w};
      float qv[8] = {q0.x,q0.y,q0.z,q0.w,q1.x,q1.y,q1.z,q1.w};
      float mv[8] = {m0.x,m0.y,m0.z,m0.w,m1.x,m1.y,m1.z,m1.w};
      #pragma unroll
      for (int e = 0; e < 8; ++e){
        int d = d0 + e;
        float cvv = cv[e];
        a[b] += cvv*(float)wf0[e] + (cvv*qv[e])*(float)wf1[e] + (cvv*mv[e])*(float)wf2[e]
              + fabsf(cvv - qv[e])*(float)wf3[e] + fabsf(cvv - mv[e])*(float)wf4[e];
        float wv = Wb_s[imin_(d, 299)*10 + imin_(lo, 9)];
        wv = (lo < 10 && d < 300) ? wv : 0.f;
        cwb[b] += cvv*wv;
      }
    }
  }
  #pragma unroll
  for (int b = 0; b < 10; ++b){
    float v = cwb[b];
    v += __shfl_xor(v, 16, 64);
    v += __shfl_xor(v, 32, 64);
    cwb[b] = v;
  }
  if (dg == 0 && lo < 10){
    #pragma unroll
    for (int b = 0; b < 10; ++b) cwb_s[w][b][lo] = cwb[b];
  }
  __asm__ volatile("s_waitcnt lgkmcnt(0)" ::: "memory");
  __builtin_amdgcn_sched_barrier(0);
  float b2v = b2[0];
  #pragma unroll
  for (int b = 0; b < 10; ++b){
    float cross = 0.f;
    #pragma unroll
    for (int k = 0; k < 10; ++k) cross += cwb_s[w][b][k]*QM_s[k*16 + lo];
    float v = a[b];
    v += __shfl_xor(v, 16, 64);
    v += __shfl_xor(v, 32, 64);
    v += CB_s[b*16 + lo] + cross;
    float tv = tanh_(v)*W2_s[lo];
    tv += __shfl_xor(tv, 1, 64);
    tv += __shfl_xor(tv, 2, 64);
    tv += __shfl_xor(tv, 4, 64);
    tv += __shfl_xor(tv, 8, 64);
    a[b] = sigm_(tv + b2v);
  }
  if (l == 0){
    #pragma unroll
    for (int b = 0; b < 10; ++b) Gout[b*2048 + t] = a[b]*mask[t*10 + b];
  }
}

// ================= K2: softmax over T per b: Gs[t][b] =================
__global__ __launch_bounds__(256) void k2_softmax(const float* __restrict__ G, float* __restrict__ Gs)
{
  int b = blockIdx.x, tid = threadIdx.x;
  __shared__ float red[4];
  float v[8];
  #pragma unroll
  for (int k = 0; k < 8; ++k) v[k] = G[b*2048 + tid + k*256];
  float mx = v[0];
  #pragma unroll
  for (int k = 1; k < 8; ++k) mx = fmaxf(mx, v[k]);
  #pragma unroll
  for (int off = 1; off < 64; off <<= 1) mx = fmaxf(mx, __shfl_xor(mx, off, 64));
  if ((tid & 63) == 0) red[tid >> 6] = mx;
  __syncthreads();
  mx = fmaxf(fmaxf(red[0], red[1]), fmaxf(red[2], red[3]));
  __syncthreads();
  float e[8], s = 0.f;
  #pragma unroll
  for (int k = 0; k < 8; ++k){ e[k] = __expf(v[k]-mx); s += e[k]; }
  #pragma unroll
  for (int off = 1; off < 64; off <<= 1) s += __shfl_xor(s, off, 64);
  if ((tid & 63) == 0) red[tid >> 6] = s;
  __syncthreads();
  s = red[0]+red[1]+red[2]+red[3];
  float inv = 1.0f / s;
  #pragma unroll
  for (int k = 0; k < 8; ++k) Gs[(tid + k*256)*10 + b] = e[k]*inv;
}

// ================= K3: gi[t] = seq[t] @ Wih + bih (+bhh folded for r,z) =================
__global__ __launch_bounds__(256) void k3_gi(
    const float* __restrict__ cs, const float* __restrict__ Gs,
    const float* __restrict__ Wih, const float* __restrict__ bih, const float* __restrict__ bhh,
    f16* __restrict__ giP)
{
  int t = blockIdx.x, tid = threadIdx.x;
  __shared__ __align__(16) float sfT[300*16];
  for (int i = tid; i < 3000; i += 256){
    int d = i / 10, bcol = i % 10;
    int jj = d % 10;
    sfT[d*16 + bcol] = Gs[t*10 + jj] * cs[((size_t)t*10 + jj)*300 + bcol*30 + d/10];
  }
  __syncthreads();
  float acc[4][10];
  #pragma unroll
  for (int jp = 0; jp < 4; ++jp)
    #pragma unroll
    for (int b = 0; b < 10; ++b) acc[jp][b] = 0.f;
  for (int d = 0; d < 300; ++d){
    float4 s0 = *(const float4*)&sfT[d*16 + 0];
    float4 s1 = *(const float4*)&sfT[d*16 + 4];
    float4 s2 = *(const float4*)&sfT[d*16 + 8];
    float sb[10] = {s0.x,s0.y,s0.z,s0.w, s1.x,s1.y,s1.z,s1.w, s2.x,s2.y};
    #pragma unroll
    for (int jp = 0; jp < 4; ++jp){
      int j = jp*256 + tid;
      float wv = Wih[(size_t)d*900 + imin_(j, 899)];
      wv = (j < 900) ? wv : 0.f;
      #pragma unroll
      for (int b = 0; b < 10; ++b) acc[jp][b] += wv * sb[b];
    }
  }
  #pragma unroll
  for (int jp = 0; jp < 4; ++jp){
    int j = jp*256 + tid;
    if (j < 900){
      int gate = j / 300, c = j - gate*300;
      int cb = c >> 4, rr = c & 15;
      int mt = gate*19 + cb, g = rr >> 2, er = rr & 3;
      float bias = bih[j] + (j < 600 ? bhh[j] : 0.f);
      size_t base = ((size_t)t*57 + mt)*256;
      #pragma unroll
      for (int b = 0; b < 10; ++b)
        giP[base + (size_t)(((g<<4)|b)*4 + er)] = (f16)(acc[jp][b] + bias);
    }
  }
}

// ================= K4 v2: 4 waves, 1 wave/SIMD, 512-VGPR budget =================
// w0-2: 5 cb each. kc0-3 VGPR, kc5/6 LDS, kc4/7/8 streamed (one 60-reg buffer,
//   WAR-rotated with MFMA phases between issue and consume), A9 in LDS.
// w3: 4 cb (cb15-18). kc0-6 VGPR, kc7/8 LDS, A9 regs. Zero stream.
// Wave-local gate trio -> combine needs no exchange. h via LDS ping-pong, 1 barrier/step.
#define BPAR 4864   // f16 per parity: 9*512 + 256

#define MFMA32(a,b,c) __builtin_amdgcn_mfma_f32_16x16x32_f16(a,b,c,0,0,0)
#define MFMA16(a,b,c) __builtin_amdgcn_mfma_f32_16x16x16f16(a,b,c,0,0,0)

__device__ __forceinline__ void publish_h(f16* Bn, int l, int bl, int c0, const f16x4& pv){
  if (c0 >= 288) *(f16x4*)&Bn[4608 + l*4] = pv;
  else {
    int kc = c0 >> 5, grp = (c0 & 31) >> 3, e0 = c0 & 7;
    *(f16x4*)&Bn[kc*512 + (grp*16 + bl)*8 + e0] = pv;
  }
}

// ---- w0..w2 body: NCB=5 ----
__device__ __forceinline__ void gru_main5(
    int w, int l, const f16* __restrict__ WhhP, const f16* __restrict__ giP,
    const float* __restrict__ mI, float* __restrict__ hout,
    f16* A_lds, f16* A9_lds, f16* Bb)
{
  const int bl = l & 15, g = l >> 4;
  const int cb0 = w*5;

  f16x8 aV[15][4];                       // kc0-3 resident (240 regs)
  #pragma unroll
  for (int ti = 0; ti < 15; ++ti){
    const int mt = (ti/5)*19 + cb0 + ti%5;
    #pragma unroll
    for (int kc = 0; kc < 4; ++kc)
      aV[ti][kc] = *(const f16x8*)&WhhP[(size_t)((mt*10+kc)*64 + l)*8];
  }
  float hreg[5][4];
  #pragma unroll
  for (int u = 0; u < 5; ++u){
    const int c0 = (cb0+u)*16 + g*4;
    #pragma unroll
    for (int rg = 0; rg < 4; ++rg){
      int c = imin_(c0 + rg, 299);
      hreg[u][rg] = (bl < 10 && c0 + rg < 300) ? mI[bl*300 + c] : 0.f;
    }
    if (bl < 10 && c0 < 300){
      f16x4 pv = {(f16)hreg[u][0], (f16)hreg[u][1], (f16)hreg[u][2], (f16)hreg[u][3]};
      publish_h(Bb, l, bl, c0, pv);
    }
  }
  __syncthreads();

  for (int t = 0; t < 2048; ++t){
    __asm__ volatile("" ::: "memory");
    const f16* Bc = Bb + (t & 1)*BPAR;
    f16* Bn = Bb + ((t & 1)^1)*BPAR;
    const f16* gp = giP + (size_t)t*14592;

    // issue gv + stream kc4 at top (latency hides under V phase)
    f16x4 gv[15];
    f16x8 sS[15];
    #pragma unroll
    for (int ti = 0; ti < 15; ++ti){
      const int mt = (ti/5)*19 + cb0 + ti%5;
      gv[ti] = *(const f16x4*)&gp[(size_t)(mt*64 + l)*4];
      sS[ti] = *(const f16x8*)&WhhP[(size_t)((mt*10+4)*64 + l)*8];
    }
    f32x4 acc[15];
    #pragma unroll
    for (int ti = 0; ti < 15; ++ti) acc[ti] = (f32x4){0.f,0.f,0.f,0.f};

    // V: kc0-3 (60 MFMA)
    #pragma unroll
    for (int kc = 0; kc < 4; ++kc){
      f16x8 bk = *(const f16x8*)&Bc[kc*512 + l*8];
      #pragma unroll
      for (int ti = 0; ti < 15; ++ti) acc[ti] = MFMA32(aV[ti][kc], bk, acc[ti]);
    }
    // kc4 (streamed), then issue kc7
    {
      f16x8 bk = *(const f16x8*)&Bc[4*512 + l*8];
      #pragma unroll
      for (int ti = 0; ti < 15; ++ti) acc[ti] = MFMA32(sS[ti], bk, acc[ti]);
    }
    #pragma unroll
    for (int ti = 0; ti < 15; ++ti){
      const int mt = (ti/5)*19 + cb0 + ti%5;
      sS[ti] = *(const f16x8*)&WhhP[(size_t)((mt*10+7)*64 + l)*8];
    }
    // L: kc5 (LDS) — covers kc7 latency
    {
      f16x8 bk = *(const f16x8*)&Bc[5*512 + l*8];
      #pragma unroll
      for (int ti = 0; ti < 15; ++ti){
        f16x8 a = *(const f16x8*)&A_lds[(size_t)((w*30 + ti*2 + 0)*512) + l*8];
        acc[ti] = MFMA32(a, bk, acc[ti]);
      }
    }
    // kc7 (streamed), then issue kc8
    {
      f16x8 bk = *(const f16x8*)&Bc[7*512 + l*8];
      #pragma unroll
      for (int ti = 0; ti < 15; ++ti) acc[ti] = MFMA32(sS[ti], bk, acc[ti]);
    }
    #pragma unroll
    for (int ti = 0; ti < 15; ++ti){
      const int mt = (ti/5)*19 + cb0 + ti%5;
      sS[ti] = *(const f16x8*)&WhhP[(size_t)((mt*10+8)*64 + l)*8];
    }
    // L: kc6 (LDS) + A9 (K16) — cover kc8 latency
    {
      f16x8 bk = *(const f16x8*)&Bc[6*512 + l*8];
      #pragma unroll
      for (int ti = 0; ti < 15; ++ti){
        f16x8 a = *(const f16x8*)&A_lds[(size_t)((w*30 + ti*2 + 1)*512) + l*8];
        acc[ti] = MFMA32(a, bk, acc[ti]);
      }
    }
    {
      f16x4 b9 = *(const f16x4*)&Bc[4608 + l*4];
      #pragma unroll
      for (int ti = 0; ti < 15; ++ti){
        f16x4 a9 = *(const f16x4*)&A9_lds[(size_t)(((ti/5)*15 + cb0 + ti%5)*256) + l*4];
        acc[ti] = MFMA16(a9, b9, acc[ti]);
      }
    }
    // kc8 (streamed)
    {
      f16x8 bk = *(const f16x8*)&Bc[8*512 + l*8];
      #pragma unroll
      for (int ti = 0; ti < 15; ++ti) acc[ti] = MFMA32(sS[ti], bk, acc[ti]);
    }
    // combine + publish
    #pragma unroll
    for (int u = 0; u < 5; ++u){
      const int c0 = (cb0+u)*16 + g*4;
      if (bl < 10 && c0 < 300){
        f16 hx[4];
        #pragma unroll
        for (int rg = 0; rg < 4; ++rg){
          float r  = sigm_(acc[u][rg]      + (float)gv[u][rg]);
          float z  = sigm_(acc[5+u][rg]    + (float)gv[5+u][rg]);
          float n  = tanh_((float)gv[10+u][rg] + r*acc[10+u][rg]);
          float hn = (1.f - z)*n + z*hreg[u][rg];
          hreg[u][rg] = hn;
          hx[rg] = (f16)hn;
        }
        f16x4 pv = {hx[0], hx[1], hx[2], hx[3]};
        publish_h(Bn, l, bl, c0, pv);
      }
    }
    __syncthreads();
  }

  #pragma unroll
  for (int u = 0; u < 5; ++u){
    const int c0 = (cb0+u)*16 + g*4;
    if (bl < 10 && c0 < 300){
      #pragma unroll
      for (int rg = 0; rg < 4; ++rg)
        hout[bl*300 + c0 + rg] = hreg[u][rg];
    }
  }
}

// ---- w3 body: NCB=4, fully resident ----
__device__ __forceinline__ void gru_main4(
    int l, const f16* __restrict__ WhhP, const f16* __restrict__ A9g,
    const f16* __restrict__ giP, const float* __restrict__ mI,
    float* __restrict__ hout, f16* A_lds, f16* Bb)
{
  const int bl = l & 15, g = l >> 4;
  const int cb0 = 15;

  f16x8 aV[12][7];                       // kc0-6 resident (336 regs)
  f16x4 s9[12];
  #pragma unroll
  for (int ti = 0; ti < 12; ++ti){
    const int mt = (ti/4)*19 + cb0 + ti%4;
    #pragma unroll
    for (int kc = 0; kc < 7; ++kc)
      aV[ti][kc] = *(const f16x8*)&WhhP[(size_t)((mt*10+kc)*64 + l)*8];
    s9[ti] = *(const f16x4*)&A9g[(size_t)(mt*64 + l)*4];
  }
  float hreg[4][4];
  #pragma unroll
  for (int u = 0; u < 4; ++u){
    const int c0 = (cb0+u)*16 + g*4;
    #pragma unroll
    for (int rg = 0; rg < 4; ++rg){
      int c = imin_(c0 + rg, 299);
      hreg[u][rg] = (bl < 10 && c0 + rg < 300) ? mI[bl*300 + c] : 0.f;
    }
    if (bl < 10 && c0 < 300){
      f16x4 pv = {(f16)hreg[u][0], (f16)hreg[u][1], (f16)hreg[u][2], (f16)hreg[u][3]};
      publish_h(Bb, l, bl, c0, pv);
    }
  }
  __syncthreads();

  for (int t = 0; t < 2048; ++t){
    __asm__ volatile("" ::: "memory");
    const f16* Bc = Bb + (t & 1)*BPAR;
    f16* Bn = Bb + ((t & 1)^1)*BPAR;
    const f16* gp = giP + (size_t)t*14592;

    f16x4 gv[12];
    #pragma unroll
    for (int ti = 0; ti < 12; ++ti){
      const int mt = (ti/4)*19 + cb0 + ti%4;
      gv[ti] = *(const f16x4*)&gp[(size_t)(mt*64 + l)*4];
    }
    f32x4 acc[12];
    #pragma unroll
    for (int ti = 0; ti < 12; ++ti) acc[ti] = (f32x4){0.f,0.f,0.f,0.f};

    // V: kc0-6
    #pragma unroll
    for (int kc = 0; kc < 7; ++kc){
      f16x8 bk = *(const f16x8*)&Bc[kc*512 + l*8];
      #pragma unroll
      for (int ti = 0; ti < 12; ++ti) acc[ti] = MFMA32(aV[ti][kc], bk, acc[ti]);
    }
    // L: kc7,kc8 (LDS, base slot 90)
    #pragma unroll
    for (int j = 0; j < 2; ++j){
      f16x8 bk = *(const f16x8*)&Bc[(7+j)*512 + l*8];
      #pragma unroll
      for (int ti = 0; ti < 12; ++ti){
        f16x8 a = *(const f16x8*)&A_lds[(size_t)((90 + ti*2 + j)*512) + l*8];
        acc[ti] = MFMA32(a, bk, acc[ti]);
      }
    }
    // A9 (K16)
    {
      f16x4 b9 = *(const f16x4*)&Bc[4608 + l*4];
      #pragma unroll
      for (int ti = 0; ti < 12; ++ti) acc[ti] = MFMA16(s9[ti], b9, acc[ti]);
    }
    // combine + publish
    #pragma unroll
    for (int u = 0; u < 4; ++u){
      const int c0 = (cb0+u)*16 + g*4;
      if (bl < 10 && c0 < 300){
        f16 hx[4];
        #pragma unroll
        for (int rg = 0; rg < 4; ++rg){
          float r  = sigm_(acc[u][rg]      + (float)gv[u][rg]);
          float z  = sigm_(acc[4+u][rg]    + (float)gv[4+u][rg]);
          float n  = tanh_((float)gv[8+u][rg] + r*acc[8+u][rg]);
          float hn = (1.f - z)*n + z*hreg[u][rg];
          hreg[u][rg] = hn;
          hx[rg] = (f16)hn;
        }
        f16x4 pv = {hx[0], hx[1], hx[2], hx[3]};
        publish_h(Bn, l, bl, c0, pv);
      }
    }
    __syncthreads();
  }

  #pragma unroll
  for (int u = 0; u < 4; ++u){
    const int c0 = (cb0+u)*16 + g*4;
    if (bl < 10 && c0 < 300){
      #pragma unroll
      for (int rg = 0; rg < 4; ++rg)
        hout[bl*300 + c0 + rg] = hreg[u][rg];
    }
  }
}

__global__ __launch_bounds__(256, 1) void k4_quad(
    const f16* __restrict__ WhhP, const f16* __restrict__ A9g,
    const f16* __restrict__ giP, const float* __restrict__ mI,
    float* __restrict__ hout)
{
  __shared__ __align__(16) f16 A_lds[114*512];   // 116736 B
  __shared__ __align__(16) f16 A9_lds[45*256];   //  23040 B
  __shared__ __align__(16) f16 Bb[2*BPAR];       //  19456 B
  const int tid = threadIdx.x;
  const int w = tid >> 6, l = tid & 63;

  uint32_t* bz = (uint32_t*)Bb;
  for (int i = tid; i < 2*BPAR/2; i += 256) bz[i] = 0u;
  __syncthreads();
  if (tid < 32){
    int p = tid >> 4, ll = 48 + (tid & 15);
    bz[p*(BPAR/2) + (9216 + ll*8)/4] = 0x00003C00u;  // f16 {1.0, 0.0} at k=300
  }

  // stage per-wave LDS A slots (+ A9 for w0-2)
  if (w < 3){
    #pragma unroll
    for (int ti = 0; ti < 15; ++ti){
      const int mt = (ti/5)*19 + w*5 + ti%5;
      #pragma unroll
      for (int j = 0; j < 2; ++j){
        f16x8 v = *(const f16x8*)&WhhP[(size_t)((mt*10+5+j)*64 + l)*8];
        *(f16x8*)&A_lds[(size_t)((w*30 + ti*2 + j)*512) + l*8] = v;
      }
      f16x4 a9 = *(const f16x4*)&A9g[(size_t)(mt*64 + l)*4];
      *(f16x4*)&A9_lds[(size_t)(((ti/5)*15 + w*5 + ti%5)*256) + l*4] = a9;
    }
  } else {
    #pragma unroll
    for (int ti = 0; ti < 12; ++ti){
      const int mt = (ti/4)*19 + 15 + ti%4;
      #pragma unroll
      for (int j = 0; j < 2; ++j){
        f16x8 v = *(const f16x8*)&WhhP[(size_t)((mt*10+7+j)*64 + l)*8];
        *(f16x8*)&A_lds[(size_t)((90 + ti*2 + j)*512) + l*8] = v;
      }
    }
  }
  __syncthreads();

  if (w < 3) gru_main5(w, l, WhhP, giP, mI, hout, A_lds, A9_lds, Bb);
  else       gru_main4(l, WhhP, A9g, giP, mI, hout, A_lds, Bb);
}

// ================= launch =================
extern "C" void kernel_launch(void* const* d_in, const int* in_sizes, int n_in,
                              void* d_out, int out_size, void* d_ws, size_t ws_size,
                              hipStream_t stream)
{
  const float* cs   = (const float*)d_in[0];
  const float* m    = (const float*)d_in[1];
  const float* q    = (const float*)d_in[2];
  const float* mask = (const float*)d_in[3];
  const float* Wb   = (const float*)d_in[4];
  const float* W1   = (const float*)d_in[5];
  const float* b1   = (const float*)d_in[6];
  const float* W2   = (const float*)d_in[7];
  const float* b2   = (const float*)d_in[8];
  const float* Wih  = (const float*)d_in[9];
  const float* Whh  = (const float*)d_in[10];
  const float* bih  = (const float*)d_in[11];
  const float* bhh  = (const float*)d_in[12];
  float* out = (float*)d_out;
  char* ws = (char*)d_ws;
  float* Gs   = (float*)(ws + WS_GS);
  float* QM   = (float*)(ws + WS_QM);
  float* CB   = (float*)(ws + WS_CB);
  f16*   W1T  = (f16*)(ws + WS_W1T);
  f16*   A9   = (f16*)(ws + WS_A9);     // overlays W1T (dead after k1)
  f16*   WhhP = (f16*)(ws + WS_WHHP);
  f16*   giP  = (f16*)(ws + WS_GIP);

  k0_prep<<<dim3(1), dim3(512), 0, stream>>>(q, m, W1, b1, QM, CB, W1T);
  k_pack<<<dim3(570), dim3(64), 0, stream>>>(Whh, WhhP);
  k1_attn<<<dim3(256), dim3(512), 0, stream>>>(cs, m, q, mask, Wb, W2, b2, QM, CB, W1T, out);
  k2_softmax<<<dim3(10), dim3(256), 0, stream>>>(out, Gs);
  k3_gi<<<dim3(2048), dim3(256), 0, stream>>>(cs, Gs, Wih, bih, bhh, giP);
  k_pack9<<<dim3(57), dim3(64), 0, stream>>>(Whh, bhh, A9);
  k4_quad<<<dim3(1), dim3(256), 0, stream>>>(WhhP, A9, giP, m, out + 20480);
}

// Round 8
// 14631.905 us; speedup vs baseline: 1.4253x; 1.4253x over previous
//
#include <hip/hip_runtime.h>
#include <hip/hip_fp16.h>
#include <cstdint>
#include <cstddef>

typedef _Float16 f16;
typedef _Float16 f16x8 __attribute__((ext_vector_type(8)));
typedef _Float16 f16x4 __attribute__((ext_vector_type(4)));
typedef float    f32x4 __attribute__((ext_vector_type(4)));

// ---------------- ws layout (bytes) ----------------
// Gs   f32 [2048][10]                :      0 ..  81920
// QM   f32 [10][16]                  :  81920 ..  82560
// CB   f32 [10][16]                  :  82560 ..  83200
// W1T  f16 [16][5][4][80]            :  83200 .. 134400   (dead after k1)
//   A9  f16 [57][64][4]  (overlay)   :  83200 .. 112384   (written after k1)
// WhhP f16 [57*10][64][8]            : 134400 .. 718080
// giP  f16 [2048][57][64][4]         : 718080 .. 60486912
#define WS_GS    0u
#define WS_QM    81920u
#define WS_CB    82560u
#define WS_W1T   83200u
#define WS_A9    83200u
#define WS_WHHP  134400u
#define WS_GIP   718080u

__device__ __forceinline__ float sigm_(float x){ return 1.0f/(1.0f + __expf(-x)); }
__device__ __forceinline__ float tanh_(float x){
  float ax = fabsf(x);
  float e  = __expf(-2.0f*ax);
  float r  = (1.0f - e)/(1.0f + e);
  return x < 0.0f ? -r : r;
}
__device__ __forceinline__ int imin_(int a,int b){ return a<b?a:b; }

// ================= K0: prep (QM, CB, W1T) =================
__global__ __launch_bounds__(512) void k0_prep(
    const float* __restrict__ q, const float* __restrict__ m,
    const float* __restrict__ W1, const float* __restrict__ b1,
    float* __restrict__ QM, float* __restrict__ CBo, f16* __restrict__ W1T)
{
  int tid = threadIdx.x;
  if (tid < 160){
    int k = tid >> 4, h = tid & 15;
    float acc = 0.f;
    for (int d = 0; d < 300; ++d)
      acc += q[k*300+d]*W1[(2100+d)*16+h] + m[k*300+d]*W1[(2400+d)*16+h];
    QM[tid] = acc;
  } else if (tid < 320){
    int b = (tid-160) >> 4, h = tid & 15;
    float acc = b1[h];
    for (int d = 0; d < 300; ++d)
      acc += m[b*300+d]*W1[(300+d)*16+h] + q[b*300+d]*W1[(600+d)*16+h];
    CBo[tid-160] = acc;
  }
  const int blkoff[5] = {0, 900, 1200, 1500, 1800};
  for (int i = tid; i < 25600; i += 512){
    int ii = i % 80; int r = i / 80;
    int dg = r % 4; r /= 4;
    int blk = r % 5; int h = r / 5;
    int d = dg*80 + ii;
    float v = 0.f;
    if (d < 300) v = W1[(blkoff[blk]+d)*16 + h];
    W1T[i] = (f16)v;
  }
}

// ================= Kpack: Whh -> MFMA A-fragment layout (f16) =================
__global__ __launch_bounds__(64) void k_pack(const float* __restrict__ Whh, f16* __restrict__ WhhP)
{
  int bid = blockIdx.x, l = threadIdx.x;
  int mt = bid / 10, kc = bid % 10;
  int gate = mt / 19, cb = mt % 19;
  int rr = l & 15, grp = l >> 4;
  int c = cb*16 + rr;
  int j = gate*300 + imin_(c, 299);
  f16x8 v;
  #pragma unroll
  for (int e = 0; e < 8; ++e){
    int d = kc*32 + grp*8 + e;
    float x = Whh[(size_t)imin_(d,299)*900 + j];
    v[e] = (f16)((d < 300 && c < 300) ? x : 0.f);
  }
  *(f16x8*)&WhhP[((size_t)bid*64 + l)*8] = v;
}

// ================= Kpack9: kc9 as K=16 A-frag, with bhh_n bias row at k-slot 300 =================
__global__ __launch_bounds__(64) void k_pack9(const float* __restrict__ Whh,
                                              const float* __restrict__ bhh,
                                              f16* __restrict__ A9)
{
  int mt = blockIdx.x, l = threadIdx.x;
  int gate = mt / 19, cb = mt % 19;
  int row = l & 15, grp = l >> 4;
  int c = cb*16 + row;
  f16x4 v;
  #pragma unroll
  for (int e = 0; e < 4; ++e){
    int d = 288 + grp*4 + e;
    float x = 0.f;
    if (c < 300){
      if (d < 300) x = Whh[(size_t)d*900 + gate*300 + c];
      else if (d == 300 && gate == 2) x = bhh[600 + c];
    }
    v[e] = (f16)x;
  }
  *(f16x4*)&A9[((size_t)mt*64 + l)*4] = v;
}

// ================= K1: attention gate -> G[b][t] (d_out[0:20480]) =================
__global__ __launch_bounds__(512) void k1_attn(
    const float* __restrict__ cs, const float* __restrict__ mI, const float* __restrict__ qI,
    const float* __restrict__ mask, const float* __restrict__ Wb,
    const float* __restrict__ W2, const float* __restrict__ b2,
    const float* __restrict__ QMg, const float* __restrict__ CBg, const f16* __restrict__ W1Tg,
    float* __restrict__ Gout)
{
  __shared__ __align__(16) float q_s[3000];
  __shared__ __align__(16) float m_s[3000];
  __shared__ float Wb_s[3000];
  __shared__ float QM_s[160], CB_s[160], W2_s[16];
  __shared__ __align__(16) f16 W1T_s[25600];
  __shared__ float cwb_s[8][10][10];
  int tid = threadIdx.x;
  for (int i = tid; i < 3000; i += 512){ q_s[i] = qI[i]; m_s[i] = mI[i]; Wb_s[i] = Wb[i]; }
  for (int i = tid; i < 160; i += 512){ QM_s[i] = QMg[i]; CB_s[i] = CBg[i]; }
  if (tid < 16) W2_s[tid] = W2[tid];
  for (int i = tid; i < 25600; i += 512) W1T_s[i] = W1Tg[i];
  __syncthreads();

  int w = tid >> 6, l = tid & 63, dg = l >> 4, lo = l & 15;
  int t = blockIdx.x*8 + w;
  float a[10], cwb[10];
  #pragma unroll
  for (int b = 0; b < 10; ++b){ a[b] = 0.f; cwb[b] = 0.f; }

  for (int i = 0; i < 10; ++i){
    int d0 = dg*80 + i*8;
    const int wbase = lo*1600 + dg*80 + i*8;
    f16x8 wf0 = *(const f16x8*)&W1T_s[wbase + 0*320];
    f16x8 wf1 = *(const f16x8*)&W1T_s[wbase + 1*320];
    f16x8 wf2 = *(const f16x8*)&W1T_s[wbase + 2*320];
    f16x8 wf3 = *(const f16x8*)&W1T_s[wbase + 3*320];
    f16x8 wf4 = *(const f16x8*)&W1T_s[wbase + 4*320];
    int dc0 = imin_(d0, 296), dc1 = imin_(d0 + 4, 296);
    #pragma unroll
    for (int b = 0; b < 10; ++b){
      const float* csb = cs + ((size_t)t*10 + b)*300;
      float4 c0 = *(const float4*)(csb + dc0);
      float4 c1 = *(const float4*)(csb + dc1);
      float4 q0 = *(const float4*)(q_s + b*300 + dc0);
      float4 q1 = *(const float4*)(q_s + b*300 + dc1);
      float4 m0 = *(const float4*)(m_s + b*300 + dc0);
      float4 m1 = *(const float4*)(m_s + b*300 + dc1);
      float cv[8] = {c0.x,c0.y,c0.z,c0.w,c1.x,c1.y,c1.z,c1.w};
      float qv[8] = {q0.x,q0.y,q0.z,q0.w,q1.x,q1.y,q1.z,q1.w};
      float mv[8] = {m0.x,m0.y,m0.z,m0.w,m1.x,m1.y,m1.z,m1.w};
      #pragma unroll
      for (int e = 0; e < 8; ++e){
        int d = d0 + e;
        float cvv = cv[e];
        a[b] += cvv*(float)wf0[e] + (cvv*qv[e])*(float)wf1[e] + (cvv*mv[e])*(float)wf2[e]
              + fabsf(cvv - qv[e])*(float)wf3[e] + fabsf(cvv - mv[e])*(float)wf4[e];
        float wv = Wb_s[imin_(d, 299)*10 + imin_(lo, 9)];
        wv = (lo < 10 && d < 300) ? wv : 0.f;
        cwb[b] += cvv*wv;
      }
    }
  }
  #pragma unroll
  for (int b = 0; b < 10; ++b){
    float v = cwb[b];
    v += __shfl_xor(v, 16, 64);
    v += __shfl_xor(v, 32, 64);
    cwb[b] = v;
  }
  if (dg == 0 && lo < 10){
    #pragma unroll
    for (int b = 0; b < 10; ++b) cwb_s[w][b][lo] = cwb[b];
  }
  __asm__ volatile("s_waitcnt lgkmcnt(0)" ::: "memory");
  __builtin_amdgcn_sched_barrier(0);
  float b2v = b2[0];
  #pragma unroll
  for (int b = 0; b < 10; ++b){
    float cross = 0.f;
    #pragma unroll
    for (int k = 0; k < 10; ++k) cross += cwb_s[w][b][k]*QM_s[k*16 + lo];
    float v = a[b];
    v += __shfl_xor(v, 16, 64);
    v += __shfl_xor(v, 32, 64);
    v += CB_s[b*16 + lo] + cross;
    float tv = tanh_(v)*W2_s[lo];
    tv += __shfl_xor(tv, 1, 64);
    tv += __shfl_xor(tv, 2, 64);
    tv += __shfl_xor(tv, 4, 64);
    tv += __shfl_xor(tv, 8, 64);
    a[b] = sigm_(tv + b2v);
  }
  if (l == 0){
    #pragma unroll
    for (int b = 0; b < 10; ++b) Gout[b*2048 + t] = a[b]*mask[t*10 + b];
  }
}

// ================= K2: softmax over T per b: Gs[t][b] =================
__global__ __launch_bounds__(256) void k2_softmax(const float* __restrict__ G, float* __restrict__ Gs)
{
  int b = blockIdx.x, tid = threadIdx.x;
  __shared__ float red[4];
  float v[8];
  #pragma unroll
  for (int k = 0; k < 8; ++k) v[k] = G[b*2048 + tid + k*256];
  float mx = v[0];
  #pragma unroll
  for (int k = 1; k < 8; ++k) mx = fmaxf(mx, v[k]);
  #pragma unroll
  for (int off = 1; off < 64; off <<= 1) mx = fmaxf(mx, __shfl_xor(mx, off, 64));
  if ((tid & 63) == 0) red[tid >> 6] = mx;
  __syncthreads();
  mx = fmaxf(fmaxf(red[0], red[1]), fmaxf(red[2], red[3]));
  __syncthreads();
  float e[8], s = 0.f;
  #pragma unroll
  for (int k = 0; k < 8; ++k){ e[k] = __expf(v[k]-mx); s += e[k]; }
  #pragma unroll
  for (int off = 1; off < 64; off <<= 1) s += __shfl_xor(s, off, 64);
  if ((tid & 63) == 0) red[tid >> 6] = s;
  __syncthreads();
  s = red[0]+red[1]+red[2]+red[3];
  float inv = 1.0f / s;
  #pragma unroll
  for (int k = 0; k < 8; ++k) Gs[(tid + k*256)*10 + b] = e[k]*inv;
}

// ================= K3: gi[t] = seq[t] @ Wih + bih (+bhh folded for r,z) =================
__global__ __launch_bounds__(256) void k3_gi(
    const float* __restrict__ cs, const float* __restrict__ Gs,
    const float* __restrict__ Wih, const float* __restrict__ bih, const float* __restrict__ bhh,
    f16* __restrict__ giP)
{
  int t = blockIdx.x, tid = threadIdx.x;
  __shared__ __align__(16) float sfT[300*16];
  for (int i = tid; i < 3000; i += 256){
    int d = i / 10, bcol = i % 10;
    int jj = d % 10;
    sfT[d*16 + bcol] = Gs[t*10 + jj] * cs[((size_t)t*10 + jj)*300 + bcol*30 + d/10];
  }
  __syncthreads();
  float acc[4][10];
  #pragma unroll
  for (int jp = 0; jp < 4; ++jp)
    #pragma unroll
    for (int b = 0; b < 10; ++b) acc[jp][b] = 0.f;
  for (int d = 0; d < 300; ++d){
    float4 s0 = *(const float4*)&sfT[d*16 + 0];
    float4 s1 = *(const float4*)&sfT[d*16 + 4];
    float4 s2 = *(const float4*)&sfT[d*16 + 8];
    float sb[10] = {s0.x,s0.y,s0.z,s0.w, s1.x,s1.y,s1.z,s1.w, s2.x,s2.y};
    #pragma unroll
    for (int jp = 0; jp < 4; ++jp){
      int j = jp*256 + tid;
      float wv = Wih[(size_t)d*900 + imin_(j, 899)];
      wv = (j < 900) ? wv : 0.f;
      #pragma unroll
      for (int b = 0; b < 10; ++b) acc[jp][b] += wv * sb[b];
    }
  }
  #pragma unroll
  for (int jp = 0; jp < 4; ++jp){
    int j = jp*256 + tid;
    if (j < 900){
      int gate = j / 300, c = j - gate*300;
      int cb = c >> 4, rr = c & 15;
      int mt = gate*19 + cb, g = rr >> 2, er = rr & 3;
      float bias = bih[j] + (j < 600 ? bhh[j] : 0.f);
      size_t base = ((size_t)t*57 + mt)*256;
      #pragma unroll
      for (int b = 0; b < 10; ++b)
        giP[base + (size_t)(((g<<4)|b)*4 + er)] = (f16)(acc[jp][b] + bias);
    }
  }
}

// ================= K4 v3: 4 waves, AGPR-pinned resident weights =================
// Arch-VGPR cap is 256; the unified file's other 256 AGPRs hold the persistent
// A-fragments, pinned via asm("" : "+a"(frag)) (opaque def -> no remat; MFMA
// reads AGPRs directly on gfx950).
// w0-2: 5 cb each. kc0-3 AGPR (240), kc5/6 LDS, kc4/7/8 + A9 + gv streamed,
//   loads issued one MFMA-phase ahead of consumption.
// w3: 4 cb. kc0-4 AGPR (240), kc5-8 LDS, A9 in VGPR. Zero stream.
// h via LDS ping-pong, 1 barrier/step.
#define BPAR 4864   // f16 per parity: 9*512 + 256

#define MFMA32(a,b,c) __builtin_amdgcn_mfma_f32_16x16x32_f16(a,b,c,0,0,0)
#define MFMA16(a,b,c) __builtin_amdgcn_mfma_f32_16x16x16f16(a,b,c,0,0,0)
#define PIN_A(x) asm volatile("" : "+a"(x))

__device__ __forceinline__ void publish_h(f16* Bn, int l, int bl, int c0, const f16x4& pv){
  if (c0 >= 288) *(f16x4*)&Bn[4608 + l*4] = pv;
  else {
    int kc = c0 >> 5, grp = (c0 & 31) >> 3, e0 = c0 & 7;
    *(f16x4*)&Bn[kc*512 + (grp*16 + bl)*8 + e0] = pv;
  }
}

// ---- w0..w2 body: NCB=5 ----
__device__ __forceinline__ void gru_main5(
    int w, int l, const f16* __restrict__ WhhP, const f16* __restrict__ A9g,
    const f16* __restrict__ giP, const float* __restrict__ mI,
    float* __restrict__ hout, f16* A_lds, f16* Bb)
{
  const int bl = l & 15, g = l >> 4;
  const int cb0 = w*5;

  f16x8 aV[15][4];                       // kc0-3 resident, pinned to AGPR (240)
  #pragma unroll
  for (int ti = 0; ti < 15; ++ti){
    const int mt = (ti/5)*19 + cb0 + ti%5;
    #pragma unroll
    for (int kc = 0; kc < 4; ++kc)
      aV[ti][kc] = *(const f16x8*)&WhhP[(size_t)((mt*10+kc)*64 + l)*8];
  }
  #pragma unroll
  for (int ti = 0; ti < 15; ++ti)
    #pragma unroll
    for (int kc = 0; kc < 4; ++kc)
      PIN_A(aV[ti][kc]);

  float hreg[5][4];
  #pragma unroll
  for (int u = 0; u < 5; ++u){
    const int c0 = (cb0+u)*16 + g*4;
    #pragma unroll
    for (int rg = 0; rg < 4; ++rg){
      int c = imin_(c0 + rg, 299);
      hreg[u][rg] = (bl < 10 && c0 + rg < 300) ? mI[bl*300 + c] : 0.f;
    }
    if (bl < 10 && c0 < 300){
      f16x4 pv = {(f16)hreg[u][0], (f16)hreg[u][1], (f16)hreg[u][2], (f16)hreg[u][3]};
      publish_h(Bb, l, bl, c0, pv);
    }
  }
  __syncthreads();

  for (int t = 0; t < 2048; ++t){
    __asm__ volatile("" ::: "memory");
    const f16* Bc = Bb + (t & 1)*BPAR;
    f16* Bn = Bb + ((t & 1)^1)*BPAR;
    const f16* gp = giP + (size_t)t*14592;

    // issue stream kc4 (latency hides under V phase)
    f16x8 sS[15];
    #pragma unroll
    for (int ti = 0; ti < 15; ++ti){
      const int mt = (ti/5)*19 + cb0 + ti%5;
      sS[ti] = *(const f16x8*)&WhhP[(size_t)((mt*10+4)*64 + l)*8];
    }
    f32x4 acc[15];
    #pragma unroll
    for (int ti = 0; ti < 15; ++ti) acc[ti] = (f32x4){0.f,0.f,0.f,0.f};

    // V: kc0-3 from AGPR (60 MFMA)
    #pragma unroll
    for (int kc = 0; kc < 4; ++kc){
      f16x8 bk = *(const f16x8*)&Bc[kc*512 + l*8];
      #pragma unroll
      for (int ti = 0; ti < 15; ++ti) acc[ti] = MFMA32(aV[ti][kc], bk, acc[ti]);
    }
    // kc4 (streamed) consume, then issue kc7
    {
      f16x8 bk = *(const f16x8*)&Bc[4*512 + l*8];
      #pragma unroll
      for (int ti = 0; ti < 15; ++ti) acc[ti] = MFMA32(sS[ti], bk, acc[ti]);
    }
    #pragma unroll
    for (int ti = 0; ti < 15; ++ti){
      const int mt = (ti/5)*19 + cb0 + ti%5;
      sS[ti] = *(const f16x8*)&WhhP[(size_t)((mt*10+7)*64 + l)*8];
    }
    // LDS kc5 — covers kc7 latency
    {
      f16x8 bk = *(const f16x8*)&Bc[5*512 + l*8];
      #pragma unroll
      for (int ti = 0; ti < 15; ++ti){
        f16x8 a = *(const f16x8*)&A_lds[(size_t)((w*30 + ti*2 + 0)*512) + l*8];
        acc[ti] = MFMA32(a, bk, acc[ti]);
      }
    }
    // kc7 consume; issue kc8 + A9 + gv
    {
      f16x8 bk = *(const f16x8*)&Bc[7*512 + l*8];
      #pragma unroll
      for (int ti = 0; ti < 15; ++ti) acc[ti] = MFMA32(sS[ti], bk, acc[ti]);
    }
    f16x4 a9r[15];
    f16x4 gv[15];
    #pragma unroll
    for (int ti = 0; ti < 15; ++ti){
      const int mt = (ti/5)*19 + cb0 + ti%5;
      sS[ti] = *(const f16x8*)&WhhP[(size_t)((mt*10+8)*64 + l)*8];
      a9r[ti] = *(const f16x4*)&A9g[(size_t)(mt*64 + l)*4];
      gv[ti]  = *(const f16x4*)&gp[(size_t)(mt*64 + l)*4];
    }
    // LDS kc6 — covers kc8/A9/gv latency
    {
      f16x8 bk = *(const f16x8*)&Bc[6*512 + l*8];
      #pragma unroll
      for (int ti = 0; ti < 15; ++ti){
        f16x8 a = *(const f16x8*)&A_lds[(size_t)((w*30 + ti*2 + 1)*512) + l*8];
        acc[ti] = MFMA32(a, bk, acc[ti]);
      }
    }
    // A9 (K16, includes bhh_n bias)
    {
      f16x4 b9 = *(const f16x4*)&Bc[4608 + l*4];
      #pragma unroll
      for (int ti = 0; ti < 15; ++ti) acc[ti] = MFMA16(a9r[ti], b9, acc[ti]);
    }
    // kc8 consume
    {
      f16x8 bk = *(const f16x8*)&Bc[8*512 + l*8];
      #pragma unroll
      for (int ti = 0; ti < 15; ++ti) acc[ti] = MFMA32(sS[ti], bk, acc[ti]);
    }
    // combine + publish
    #pragma unroll
    for (int u = 0; u < 5; ++u){
      const int c0 = (cb0+u)*16 + g*4;
      if (bl < 10 && c0 < 300){
        f16 hx[4];
        #pragma unroll
        for (int rg = 0; rg < 4; ++rg){
          float r  = sigm_(acc[u][rg]      + (float)gv[u][rg]);
          float z  = sigm_(acc[5+u][rg]    + (float)gv[5+u][rg]);
          float n  = tanh_((float)gv[10+u][rg] + r*acc[10+u][rg]);
          float hn = (1.f - z)*n + z*hreg[u][rg];
          hreg[u][rg] = hn;
          hx[rg] = (f16)hn;
        }
        f16x4 pv = {hx[0], hx[1], hx[2], hx[3]};
        publish_h(Bn, l, bl, c0, pv);
      }
    }
    __syncthreads();
  }

  #pragma unroll
  for (int u = 0; u < 5; ++u){
    const int c0 = (cb0+u)*16 + g*4;
    if (bl < 10 && c0 < 300){
      #pragma unroll
      for (int rg = 0; rg < 4; ++rg)
        hout[bl*300 + c0 + rg] = hreg[u][rg];
    }
  }
}

// ---- w3 body: NCB=4 ----
__device__ __forceinline__ void gru_main4(
    int l, const f16* __restrict__ WhhP, const f16* __restrict__ A9g,
    const f16* __restrict__ giP, const float* __restrict__ mI,
    float* __restrict__ hout, f16* A_lds, f16* Bb)
{
  const int bl = l & 15, g = l >> 4;
  const int cb0 = 15;

  f16x8 aV[12][5];                       // kc0-4 resident, pinned to AGPR (240)
  f16x4 s9[12];
  #pragma unroll
  for (int ti = 0; ti < 12; ++ti){
    const int mt = (ti/4)*19 + cb0 + ti%4;
    #pragma unroll
    for (int kc = 0; kc < 5; ++kc)
      aV[ti][kc] = *(const f16x8*)&WhhP[(size_t)((mt*10+kc)*64 + l)*8];
    s9[ti] = *(const f16x4*)&A9g[(size_t)(mt*64 + l)*4];
  }
  #pragma unroll
  for (int ti = 0; ti < 12; ++ti)
    #pragma unroll
    for (int kc = 0; kc < 5; ++kc)
      PIN_A(aV[ti][kc]);

  float hreg[4][4];
  #pragma unroll
  for (int u = 0; u < 4; ++u){
    const int c0 = (cb0+u)*16 + g*4;
    #pragma unroll
    for (int rg = 0; rg < 4; ++rg){
      int c = imin_(c0 + rg, 299);
      hreg[u][rg] = (bl < 10 && c0 + rg < 300) ? mI[bl*300 + c] : 0.f;
    }
    if (bl < 10 && c0 < 300){
      f16x4 pv = {(f16)hreg[u][0], (f16)hreg[u][1], (f16)hreg[u][2], (f16)hreg[u][3]};
      publish_h(Bb, l, bl, c0, pv);
    }
  }
  __syncthreads();

  for (int t = 0; t < 2048; ++t){
    __asm__ volatile("" ::: "memory");
    const f16* Bc = Bb + (t & 1)*BPAR;
    f16* Bn = Bb + ((t & 1)^1)*BPAR;
    const f16* gp = giP + (size_t)t*14592;

    f16x4 gv[12];
    #pragma unroll
    for (int ti = 0; ti < 12; ++ti){
      const int mt = (ti/4)*19 + cb0 + ti%4;
      gv[ti] = *(const f16x4*)&gp[(size_t)(mt*64 + l)*4];
    }
    f32x4 acc[12];
    #pragma unroll
    for (int ti = 0; ti < 12; ++ti) acc[ti] = (f32x4){0.f,0.f,0.f,0.f};

    // V: kc0-4 from AGPR
    #pragma unroll
    for (int kc = 0; kc < 5; ++kc){
      f16x8 bk = *(const f16x8*)&Bc[kc*512 + l*8];
      #pragma unroll
      for (int ti = 0; ti < 12; ++ti) acc[ti] = MFMA32(aV[ti][kc], bk, acc[ti]);
    }
    // LDS kc5-8 (slots 90 + ti*4 + j)
    #pragma unroll
    for (int j = 0; j < 4; ++j){
      f16x8 bk = *(const f16x8*)&Bc[(5+j)*512 + l*8];
      #pragma unroll
      for (int ti = 0; ti < 12; ++ti){
        f16x8 a = *(const f16x8*)&A_lds[(size_t)((90 + ti*4 + j)*512) + l*8];
        acc[ti] = MFMA32(a, bk, acc[ti]);
      }
    }
    // A9 (K16)
    {
      f16x4 b9 = *(const f16x4*)&Bc[4608 + l*4];
      #pragma unroll
      for (int ti = 0; ti < 12; ++ti) acc[ti] = MFMA16(s9[ti], b9, acc[ti]);
    }
    // combine + publish
    #pragma unroll
    for (int u = 0; u < 4; ++u){
      const int c0 = (cb0+u)*16 + g*4;
      if (bl < 10 && c0 < 300){
        f16 hx[4];
        #pragma unroll
        for (int rg = 0; rg < 4; ++rg){
          float r  = sigm_(acc[u][rg]      + (float)gv[u][rg]);
          float z  = sigm_(acc[4+u][rg]    + (float)gv[4+u][rg]);
          float n  = tanh_((float)gv[8+u][rg] + r*acc[8+u][rg]);
          float hn = (1.f - z)*n + z*hreg[u][rg];
          hreg[u][rg] = hn;
          hx[rg] = (f16)hn;
        }
        f16x4 pv = {hx[0], hx[1], hx[2], hx[3]};
        publish_h(Bn, l, bl, c0, pv);
      }
    }
    __syncthreads();
  }

  #pragma unroll
  for (int u = 0; u < 4; ++u){
    const int c0 = (cb0+u)*16 + g*4;
    if (bl < 10 && c0 < 300){
      #pragma unroll
      for (int rg = 0; rg < 4; ++rg)
        hout[bl*300 + c0 + rg] = hreg[u][rg];
    }
  }
}

__global__ __launch_bounds__(256, 1) void k4_quad(
    const f16* __restrict__ WhhP, const f16* __restrict__ A9g,
    const f16* __restrict__ giP, const float* __restrict__ mI,
    float* __restrict__ hout)
{
  __shared__ __align__(16) f16 A_lds[138*512];   // 141312 B
  __shared__ __align__(16) f16 Bb[2*BPAR];       //  19456 B
  const int tid = threadIdx.x;
  const int w = tid >> 6, l = tid & 63;

  uint32_t* bz = (uint32_t*)Bb;
  for (int i = tid; i < 2*BPAR/2; i += 256) bz[i] = 0u;
  __syncthreads();
  if (tid < 32){
    int p = tid >> 4, ll = 48 + (tid & 15);
    bz[p*(BPAR/2) + (9216 + ll*8)/4] = 0x00003C00u;  // f16 {1.0, 0.0} at k=300
  }

  // stage per-wave LDS A slots
  if (w < 3){
    #pragma unroll
    for (int ti = 0; ti < 15; ++ti){
      const int mt = (ti/5)*19 + w*5 + ti%5;
      #pragma unroll
      for (int j = 0; j < 2; ++j){
        f16x8 v = *(const f16x8*)&WhhP[(size_t)((mt*10+5+j)*64 + l)*8];
        *(f16x8*)&A_lds[(size_t)((w*30 + ti*2 + j)*512) + l*8] = v;
      }
    }
  } else {
    #pragma unroll
    for (int ti = 0; ti < 12; ++ti){
      const int mt = (ti/4)*19 + 15 + ti%4;
      #pragma unroll
      for (int j = 0; j < 4; ++j){
        f16x8 v = *(const f16x8*)&WhhP[(size_t)((mt*10+5+j)*64 + l)*8];
        *(f16x8*)&A_lds[(size_t)((90 + ti*4 + j)*512) + l*8] = v;
      }
    }
  }
  __syncthreads();

  if (w < 3) gru_main5(w, l, WhhP, A9g, giP, mI, hout, A_lds, Bb);
  else       gru_main4(l, WhhP, A9g, giP, mI, hout, A_lds, Bb);
}

// ================= launch =================
extern "C" void kernel_launch(void* const* d_in, const int* in_sizes, int n_in,
                              void* d_out, int out_size, void* d_ws, size_t ws_size,
                              hipStream_t stream)
{
  const float* cs   = (const float*)d_in[0];
  const float* m    = (const float*)d_in[1];
  const float* q    = (const float*)d_in[2];
  const float* mask = (const float*)d_in[3];
  const float* Wb   = (const float*)d_in[4];
  const float* W1   = (const float*)d_in[5];
  const float* b1   = (const float*)d_in[6];
  const float* W2   = (const float*)d_in[7];
  const float* b2   = (const float*)d_in[8];
  const float* Wih  = (const float*)d_in[9];
  const float* Whh  = (const float*)d_in[10];
  const float* bih  = (const float*)d_in[11];
  const float* bhh  = (const float*)d_in[12];
  float* out = (float*)d_out;
  char* ws = (char*)d_ws;
  float* Gs   = (float*)(ws + WS_GS);
  float* QM   = (float*)(ws + WS_QM);
  float* CB   = (float*)(ws + WS_CB);
  f16*   W1T  = (f16*)(ws + WS_W1T);
  f16*   A9   = (f16*)(ws + WS_A9);     // overlays W1T (dead after k1)
  f16*   WhhP = (f16*)(ws + WS_WHHP);
  f16*   giP  = (f16*)(ws + WS_GIP);

  k0_prep<<<dim3(1), dim3(512), 0, stream>>>(q, m, W1, b1, QM, CB, W1T);
  k_pack<<<dim3(570), dim3(64), 0, stream>>>(Whh, WhhP);
  k1_attn<<<dim3(256), dim3(512), 0, stream>>>(cs, m, q, mask, Wb, W2, b2, QM, CB, W1T, out);
  k2_softmax<<<dim3(10), dim3(256), 0, stream>>>(out, Gs);
  k3_gi<<<dim3(2048), dim3(256), 0, stream>>>(cs, Gs, Wih, bih, bhh, giP);
  k_pack9<<<dim3(57), dim3(64), 0, stream>>>(Whh, bhh, A9);
  k4_quad<<<dim3(1), dim3(256), 0, stream>>>(WhhP, A9, giP, m, out + 20480);
}

// Round 9
// 6859.467 us; speedup vs baseline: 3.0404x; 2.1331x over previous
//
#include <hip/hip_runtime.h>
#include <hip/hip_fp16.h>
#include <cstdint>
#include <cstddef>

typedef _Float16 f16;
typedef _Float16 f16x8 __attribute__((ext_vector_type(8)));
typedef _Float16 f16x4 __attribute__((ext_vector_type(4)));
typedef float    f32x4 __attribute__((ext_vector_type(4)));

// ---------------- ws layout (bytes) ----------------
// Gs   f32 [2048][10]                :      0 ..  81920
// QM   f32 [10][16]                  :  81920 ..  82560
// CB   f32 [10][16]                  :  82560 ..  83200
// W1T  f16 [16][5][4][80]            :  83200 .. 134400   (dead after k1)
//   hbuf u64 [2][1280]  (overlay)    :  83200 .. 103680
//   flags u32[19][16]   (overlay)    : 103680 .. 104960
// WhhP f16 [57*10][64][8]            : 134400 .. 718080
// giP  f16 [2048][57][64][4]         : 718080 .. 60486912
#define WS_GS    0u
#define WS_QM    81920u
#define WS_CB    82560u
#define WS_W1T   83200u
#define WS_HBUF  83200u
#define WS_FLAGS 103680u
#define WS_WHHP  134400u
#define WS_GIP   718080u

#define HB64 1280       // u64 per parity buffer: 10*64*16B = 10240 B
#define SPIN_CAP 2000000

__device__ __forceinline__ float sigm_(float x){ return 1.0f/(1.0f + __expf(-x)); }
__device__ __forceinline__ float tanh_(float x){
  float ax = fabsf(x);
  float e  = __expf(-2.0f*ax);
  float r  = (1.0f - e)/(1.0f + e);
  return x < 0.0f ? -r : r;
}
__device__ __forceinline__ int imin_(int a,int b){ return a<b?a:b; }

// ================= K0: prep (QM, CB, W1T) =================
__global__ __launch_bounds__(512) void k0_prep(
    const float* __restrict__ q, const float* __restrict__ m,
    const float* __restrict__ W1, const float* __restrict__ b1,
    float* __restrict__ QM, float* __restrict__ CBo, f16* __restrict__ W1T)
{
  int tid = threadIdx.x;
  if (tid < 160){
    int k = tid >> 4, h = tid & 15;
    float acc = 0.f;
    for (int d = 0; d < 300; ++d)
      acc += q[k*300+d]*W1[(2100+d)*16+h] + m[k*300+d]*W1[(2400+d)*16+h];
    QM[tid] = acc;
  } else if (tid < 320){
    int b = (tid-160) >> 4, h = tid & 15;
    float acc = b1[h];
    for (int d = 0; d < 300; ++d)
      acc += m[b*300+d]*W1[(300+d)*16+h] + q[b*300+d]*W1[(600+d)*16+h];
    CBo[tid-160] = acc;
  }
  const int blkoff[5] = {0, 900, 1200, 1500, 1800};
  for (int i = tid; i < 25600; i += 512){
    int ii = i % 80; int r = i / 80;
    int dg = r % 4; r /= 4;
    int blk = r % 5; int h = r / 5;
    int d = dg*80 + ii;
    float v = 0.f;
    if (d < 300) v = W1[(blkoff[blk]+d)*16 + h];
    W1T[i] = (f16)v;
  }
}

// ================= Kpack: Whh -> MFMA A-fragment layout (f16) =================
__global__ __launch_bounds__(64) void k_pack(const float* __restrict__ Whh, f16* __restrict__ WhhP)
{
  int bid = blockIdx.x, l = threadIdx.x;
  int mt = bid / 10, kc = bid % 10;
  int gate = mt / 19, cb = mt % 19;
  int rr = l & 15, grp = l >> 4;
  int c = cb*16 + rr;
  int j = gate*300 + imin_(c, 299);
  f16x8 v;
  #pragma unroll
  for (int e = 0; e < 8; ++e){
    int d = kc*32 + grp*8 + e;
    float x = Whh[(size_t)imin_(d,299)*900 + j];
    v[e] = (f16)((d < 300 && c < 300) ? x : 0.f);
  }
  *(f16x8*)&WhhP[((size_t)bid*64 + l)*8] = v;
}

// ================= K1: attention gate -> G[b][t] (d_out[0:20480]) =================
__global__ __launch_bounds__(512) void k1_attn(
    const float* __restrict__ cs, const float* __restrict__ mI, const float* __restrict__ qI,
    const float* __restrict__ mask, const float* __restrict__ Wb,
    const float* __restrict__ W2, const float* __restrict__ b2,
    const float* __restrict__ QMg, const float* __restrict__ CBg, const f16* __restrict__ W1Tg,
    float* __restrict__ Gout)
{
  __shared__ __align__(16) float q_s[3000];
  __shared__ __align__(16) float m_s[3000];
  __shared__ float Wb_s[3000];
  __shared__ float QM_s[160], CB_s[160], W2_s[16];
  __shared__ __align__(16) f16 W1T_s[25600];
  __shared__ float cwb_s[8][10][10];
  int tid = threadIdx.x;
  for (int i = tid; i < 3000; i += 512){ q_s[i] = qI[i]; m_s[i] = mI[i]; Wb_s[i] = Wb[i]; }
  for (int i = tid; i < 160; i += 512){ QM_s[i] = QMg[i]; CB_s[i] = CBg[i]; }
  if (tid < 16) W2_s[tid] = W2[tid];
  for (int i = tid; i < 25600; i += 512) W1T_s[i] = W1Tg[i];
  __syncthreads();

  int w = tid >> 6, l = tid & 63, dg = l >> 4, lo = l & 15;
  int t = blockIdx.x*8 + w;
  float a[10], cwb[10];
  #pragma unroll
  for (int b = 0; b < 10; ++b){ a[b] = 0.f; cwb[b] = 0.f; }

  for (int i = 0; i < 10; ++i){
    int d0 = dg*80 + i*8;
    const int wbase = lo*1600 + dg*80 + i*8;
    f16x8 wf0 = *(const f16x8*)&W1T_s[wbase + 0*320];
    f16x8 wf1 = *(const f16x8*)&W1T_s[wbase + 1*320];
    f16x8 wf2 = *(const f16x8*)&W1T_s[wbase + 2*320];
    f16x8 wf3 = *(const f16x8*)&W1T_s[wbase + 3*320];
    f16x8 wf4 = *(const f16x8*)&W1T_s[wbase + 4*320];
    int dc0 = imin_(d0, 296), dc1 = imin_(d0 + 4, 296);
    #pragma unroll
    for (int b = 0; b < 10; ++b){
      const float* csb = cs + ((size_t)t*10 + b)*300;
      float4 c0 = *(const float4*)(csb + dc0);
      float4 c1 = *(const float4*)(csb + dc1);
      float4 q0 = *(const float4*)(q_s + b*300 + dc0);
      float4 q1 = *(const float4*)(q_s + b*300 + dc1);
      float4 m0 = *(const float4*)(m_s + b*300 + dc0);
      float4 m1 = *(const float4*)(m_s + b*300 + dc1);
      float cv[8] = {c0.x,c0.y,c0.z,c0.w,c1.x,c1.y,c1.z,c1.w};
      float qv[8] = {q0.x,q0.y,q0.z,q0.w,q1.x,q1.y,q1.z,q1.w};
      float mv[8] = {m0.x,m0.y,m0.z,m0.w,m1.x,m1.y,m1.z,m1.w};
      #pragma unroll
      for (int e = 0; e < 8; ++e){
        int d = d0 + e;
        float cvv = cv[e];
        a[b] += cvv*(float)wf0[e] + (cvv*qv[e])*(float)wf1[e] + (cvv*mv[e])*(float)wf2[e]
              + fabsf(cvv - qv[e])*(float)wf3[e] + fabsf(cvv - mv[e])*(float)wf4[e];
        float wv = Wb_s[imin_(d, 299)*10 + imin_(lo, 9)];
        wv = (lo < 10 && d < 300) ? wv : 0.f;
        cwb[b] += cvv*wv;
      }
    }
  }
  #pragma unroll
  for (int b = 0; b < 10; ++b){
    float v = cwb[b];
    v += __shfl_xor(v, 16, 64);
    v += __shfl_xor(v, 32, 64);
    cwb[b] = v;
  }
  if (dg == 0 && lo < 10){
    #pragma unroll
    for (int b = 0; b < 10; ++b) cwb_s[w][b][lo] = cwb[b];
  }
  __asm__ volatile("s_waitcnt lgkmcnt(0)" ::: "memory");
  __builtin_amdgcn_sched_barrier(0);
  float b2v = b2[0];
  #pragma unroll
  for (int b = 0; b < 10; ++b){
    float cross = 0.f;
    #pragma unroll
    for (int k = 0; k < 10; ++k) cross += cwb_s[w][b][k]*QM_s[k*16 + lo];
    float v = a[b];
    v += __shfl_xor(v, 16, 64);
    v += __shfl_xor(v, 32, 64);
    v += CB_s[b*16 + lo] + cross;
    float tv = tanh_(v)*W2_s[lo];
    tv += __shfl_xor(tv, 1, 64);
    tv += __shfl_xor(tv, 2, 64);
    tv += __shfl_xor(tv, 4, 64);
    tv += __shfl_xor(tv, 8, 64);
    a[b] = sigm_(tv + b2v);
  }
  if (l == 0){
    #pragma unroll
    for (int b = 0; b < 10; ++b) Gout[b*2048 + t] = a[b]*mask[t*10 + b];
  }
}

// ================= K2: softmax over T per b: Gs[t][b] =================
__global__ __launch_bounds__(256) void k2_softmax(const float* __restrict__ G, float* __restrict__ Gs)
{
  int b = blockIdx.x, tid = threadIdx.x;
  __shared__ float red[4];
  float v[8];
  #pragma unroll
  for (int k = 0; k < 8; ++k) v[k] = G[b*2048 + tid + k*256];
  float mx = v[0];
  #pragma unroll
  for (int k = 1; k < 8; ++k) mx = fmaxf(mx, v[k]);
  #pragma unroll
  for (int off = 1; off < 64; off <<= 1) mx = fmaxf(mx, __shfl_xor(mx, off, 64));
  if ((tid & 63) == 0) red[tid >> 6] = mx;
  __syncthreads();
  mx = fmaxf(fmaxf(red[0], red[1]), fmaxf(red[2], red[3]));
  __syncthreads();
  float e[8], s = 0.f;
  #pragma unroll
  for (int k = 0; k < 8; ++k){ e[k] = __expf(v[k]-mx); s += e[k]; }
  #pragma unroll
  for (int off = 1; off < 64; off <<= 1) s += __shfl_xor(s, off, 64);
  if ((tid & 63) == 0) red[tid >> 6] = s;
  __syncthreads();
  s = red[0]+red[1]+red[2]+red[3];
  float inv = 1.0f / s;
  #pragma unroll
  for (int k = 0; k < 8; ++k) Gs[(tid + k*256)*10 + b] = e[k]*inv;
}

// ================= K3: gi[t] = seq[t] @ Wih + bih (+bhh folded for r,z) =================
__global__ __launch_bounds__(256) void k3_gi(
    const float* __restrict__ cs, const float* __restrict__ Gs,
    const float* __restrict__ Wih, const float* __restrict__ bih, const float* __restrict__ bhh,
    f16* __restrict__ giP)
{
  int t = blockIdx.x, tid = threadIdx.x;
  __shared__ __align__(16) float sfT[300*16];
  for (int i = tid; i < 3000; i += 256){
    int d = i / 10, bcol = i % 10;
    int jj = d % 10;
    sfT[d*16 + bcol] = Gs[t*10 + jj] * cs[((size_t)t*10 + jj)*300 + bcol*30 + d/10];
  }
  __syncthreads();
  float acc[4][10];
  #pragma unroll
  for (int jp = 0; jp < 4; ++jp)
    #pragma unroll
    for (int b = 0; b < 10; ++b) acc[jp][b] = 0.f;
  for (int d = 0; d < 300; ++d){
    float4 s0 = *(const float4*)&sfT[d*16 + 0];
    float4 s1 = *(const float4*)&sfT[d*16 + 4];
    float4 s2 = *(const float4*)&sfT[d*16 + 8];
    float sb[10] = {s0.x,s0.y,s0.z,s0.w, s1.x,s1.y,s1.z,s1.w, s2.x,s2.y};
    #pragma unroll
    for (int jp = 0; jp < 4; ++jp){
      int j = jp*256 + tid;
      float wv = Wih[(size_t)d*900 + imin_(j, 899)];
      wv = (j < 900) ? wv : 0.f;
      #pragma unroll
      for (int b = 0; b < 10; ++b) acc[jp][b] += wv * sb[b];
    }
  }
  #pragma unroll
  for (int jp = 0; jp < 4; ++jp){
    int j = jp*256 + tid;
    if (j < 900){
      int gate = j / 300, c = j - gate*300;
      int cb = c >> 4, rr = c & 15;
      int mt = gate*19 + cb, g = rr >> 2, er = rr & 3;
      float bias = bih[j] + (j < 600 ? bhh[j] : 0.f);
      size_t base = ((size_t)t*57 + mt)*256;
      #pragma unroll
      for (int b = 0; b < 10; ++b)
        giP[base + (size_t)(((g<<4)|b)*4 + er)] = (f16)(acc[jp][b] + bias);
    }
  }
}

// ================= K4 v4: 19 WGs x 1 wave, zero intra-WG sync =================
// WG cb (0..18) owns h-columns c = cb*16..cb*16+15, ALL 3 gates (3 tiles, K=320).
// areg[3][10] = 120 VGPRs resident (pinned "+v": no remat, no AGPR penalty).
// Lane (g = l>>4, bl = l&15) holds rows c0 = cb*16+g*4..+3 for batch bl ->
// r,z,n land in the SAME lane: combine is in-lane, no LDS, no barrier.
// Per step: gi loads (h-independent, issued first) -> poll 19 flags (one
// vector load across lanes) -> 20 agent u64 loads of h_t -> 30 MFMA ->
// combine -> publish h_{t+1} (1 u64/lane) -> release flag. r2's WAR
// invariant: flag k >= t+1 ==> WG k finished reading h_{t-1}.
#define PIN_V(x) asm volatile("" : "+v"(x))

__global__ __launch_bounds__(64, 1) void k4_mesh(
    const f16* __restrict__ WhhP, const f16* __restrict__ giP,
    const float* __restrict__ mI, const float* __restrict__ bhh,
    unsigned long long* hbuf, unsigned int* flags, float* __restrict__ hout)
{
  const int cb = blockIdx.x, l = threadIdx.x;
  const int bl = l & 15, g = l >> 4;
  const int c0 = cb*16 + g*4;
  const bool wv = (c0 < 300) && (bl < 10);

  // resident A fragments: 3 gates x 10 kc (120 VGPRs), pinned
  f16x8 areg[3][10];
  #pragma unroll
  for (int gate = 0; gate < 3; ++gate){
    const int mt = gate*19 + cb;
    #pragma unroll
    for (int kc = 0; kc < 10; ++kc)
      areg[gate][kc] = *(const f16x8*)&WhhP[((size_t)(mt*10+kc)*64 + l)*8];
  }
  #pragma unroll
  for (int gate = 0; gate < 3; ++gate)
    #pragma unroll
    for (int kc = 0; kc < 10; ++kc)
      PIN_V(areg[gate][kc]);

  // h0 master (f32) + n-gate bias
  float hreg[4], bhhN[4];
  #pragma unroll
  for (int rg = 0; rg < 4; ++rg){
    int c = imin_(c0 + rg, 299);
    hreg[rg] = wv ? mI[bl*300 + c] : 0.f;
    bhhN[rg] = (c0 + rg < 300) ? bhh[600 + c] : 0.f;
  }
  // publish h0 into parity 0 (pads pre-zeroed by memset)
  if (wv){
    union { f16 h4[4]; unsigned long long u; } pk;
    #pragma unroll
    for (int rg = 0; rg < 4; ++rg) pk.h4[rg] = (f16)hreg[rg];
    int kc = c0 >> 5, grp = (c0 & 31) >> 3, e0 = c0 & 7;
    __hip_atomic_store(&hbuf[(size_t)(kc*64 + grp*16 + bl)*2 + (e0>>2)], pk.u,
                       __ATOMIC_RELAXED, __HIP_MEMORY_SCOPE_AGENT);
  }
  if (l == 0)
    __hip_atomic_store(&flags[cb*16], 1u, __ATOMIC_RELEASE, __HIP_MEMORY_SCOPE_AGENT);

  for (int t = 0; t < 2048; ++t){
    // gi for this step — independent of h, issue before the exchange
    f16x4 gv[3];
    const f16* gp = giP + (size_t)t*14592;
    #pragma unroll
    for (int gate = 0; gate < 3; ++gate)
      gv[gate] = *(const f16x4*)&gp[(size_t)((gate*19+cb)*64 + l)*4];

    // poll: lane k (k<19) watches flag k (own flag trivially satisfied)
    unsigned tgt = (unsigned)(t + 1);
    if (l < 19){
      int it = 0;
      while (__hip_atomic_load(&flags[l*16], __ATOMIC_RELAXED, __HIP_MEMORY_SCOPE_AGENT) < tgt){
        if (++it > SPIN_CAP) break;   // fail-fast: wrong answer instead of hang
      }
    }
    __builtin_amdgcn_sched_barrier(0);

    // load h_t B-fragments (20 independent agent loads)
    const unsigned long long* hb = hbuf + (size_t)(t & 1)*HB64;
    f16x8 bf[10];
    #pragma unroll
    for (int kc = 0; kc < 10; ++kc){
      union { unsigned long long u[2]; f16x8 v; } cv;
      cv.u[0] = __hip_atomic_load(&hb[(size_t)(kc*64 + l)*2 + 0], __ATOMIC_RELAXED, __HIP_MEMORY_SCOPE_AGENT);
      cv.u[1] = __hip_atomic_load(&hb[(size_t)(kc*64 + l)*2 + 1], __ATOMIC_RELAXED, __HIP_MEMORY_SCOPE_AGENT);
      bf[kc] = cv.v;
    }

    // 30 MFMA, 3 independent chains
    f32x4 a0 = {0.f,0.f,0.f,0.f}, a1 = {0.f,0.f,0.f,0.f}, a2 = {0.f,0.f,0.f,0.f};
    #pragma unroll
    for (int kc = 0; kc < 10; ++kc){
      a0 = __builtin_amdgcn_mfma_f32_16x16x32_f16(areg[0][kc], bf[kc], a0, 0, 0, 0);
      a1 = __builtin_amdgcn_mfma_f32_16x16x32_f16(areg[1][kc], bf[kc], a1, 0, 0, 0);
      a2 = __builtin_amdgcn_mfma_f32_16x16x32_f16(areg[2][kc], bf[kc], a2, 0, 0, 0);
    }

    // in-lane combine + publish h_{t+1}
    if (wv){
      union { f16 h4[4]; unsigned long long u; } pk;
      #pragma unroll
      for (int rg = 0; rg < 4; ++rg){
        float r  = sigm_(a0[rg] + (float)gv[0][rg]);
        float z  = sigm_(a1[rg] + (float)gv[1][rg]);
        float n  = tanh_((float)gv[2][rg] + r*(a2[rg] + bhhN[rg]));
        float hn = (1.f - z)*n + z*hreg[rg];
        hreg[rg] = hn;
        pk.h4[rg] = (f16)hn;
      }
      int kc = c0 >> 5, grp = (c0 & 31) >> 3, e0 = c0 & 7;
      __hip_atomic_store(&hbuf[(size_t)((t+1)&1)*HB64 + (size_t)(kc*64 + grp*16 + bl)*2 + (e0>>2)],
                         pk.u, __ATOMIC_RELAXED, __HIP_MEMORY_SCOPE_AGENT);
    }
    if (l == 0)
      __hip_atomic_store(&flags[cb*16], (unsigned)(t + 2),
                         __ATOMIC_RELEASE, __HIP_MEMORY_SCOPE_AGENT);
  }

  // final h (exact f32 master)
  if (wv){
    #pragma unroll
    for (int rg = 0; rg < 4; ++rg)
      hout[bl*300 + c0 + rg] = hreg[rg];
  }
}

// ================= launch =================
extern "C" void kernel_launch(void* const* d_in, const int* in_sizes, int n_in,
                              void* d_out, int out_size, void* d_ws, size_t ws_size,
                              hipStream_t stream)
{
  const float* cs   = (const float*)d_in[0];
  const float* m    = (const float*)d_in[1];
  const float* q    = (const float*)d_in[2];
  const float* mask = (const float*)d_in[3];
  const float* Wb   = (const float*)d_in[4];
  const float* W1   = (const float*)d_in[5];
  const float* b1   = (const float*)d_in[6];
  const float* W2   = (const float*)d_in[7];
  const float* b2   = (const float*)d_in[8];
  const float* Wih  = (const float*)d_in[9];
  const float* Whh  = (const float*)d_in[10];
  const float* bih  = (const float*)d_in[11];
  const float* bhh  = (const float*)d_in[12];
  float* out = (float*)d_out;
  char* ws = (char*)d_ws;
  float* Gs   = (float*)(ws + WS_GS);
  float* QM   = (float*)(ws + WS_QM);
  float* CB   = (float*)(ws + WS_CB);
  f16*   W1T  = (f16*)(ws + WS_W1T);
  f16*   WhhP = (f16*)(ws + WS_WHHP);
  f16*   giP  = (f16*)(ws + WS_GIP);
  unsigned long long* hbuf = (unsigned long long*)(ws + WS_HBUF);
  unsigned int* flags = (unsigned int*)(ws + WS_FLAGS);

  k0_prep<<<dim3(1), dim3(512), 0, stream>>>(q, m, W1, b1, QM, CB, W1T);
  k_pack<<<dim3(570), dim3(64), 0, stream>>>(Whh, WhhP);
  k1_attn<<<dim3(256), dim3(512), 0, stream>>>(cs, m, q, mask, Wb, W2, b2, QM, CB, W1T, out);
  k2_softmax<<<dim3(10), dim3(256), 0, stream>>>(out, Gs);
  k3_gi<<<dim3(2048), dim3(256), 0, stream>>>(cs, Gs, Wih, bih, bhh, giP);
  // W1T region dead after k1 -> reuse for hbuf (zeroed pads) + flags
  hipMemsetAsync(ws + WS_HBUF, 0, 20480 + 1280, stream);
  k4_mesh<<<dim3(19), dim3(64), 0, stream>>>(WhhP, giP, m, bhh, hbuf, flags, out + 20480);
}

// Round 10
// 5147.922 us; speedup vs baseline: 4.0513x; 1.3325x over previous
//
#include <hip/hip_runtime.h>
#include <hip/hip_fp16.h>
#include <cstdint>
#include <cstddef>

typedef _Float16 f16;
typedef _Float16 f16x8 __attribute__((ext_vector_type(8)));
typedef _Float16 f16x4 __attribute__((ext_vector_type(4)));
typedef float    f32x4 __attribute__((ext_vector_type(4)));

// ---------------- ws layout (bytes) ----------------
// Gs   f32 [2048][10]                :      0 ..  81920
// QM   f32 [10][16]                  :  81920 ..  82560
// CB   f32 [10][16]                  :  82560 ..  83200
// W1T  f16 [16][5][4][80]            :  83200 .. 134400   (dead after k1)
//   hx  u64 [4][1216]   (overlay)    :  83200 .. 122112   (sentinel exchange)
// WhhP f16 [57*10][64][8]            : 134400 .. 718080
// giP  f16 [2048][57][64][4]         : 718080 .. 60486912
#define WS_GS    0u
#define WS_QM    81920u
#define WS_CB    82560u
#define WS_W1T   83200u
#define WS_HX    83200u
#define WS_WHHP  134400u
#define WS_GIP   718080u

#define HPAR 1216        // u64 per parity: 76 cg * 16 bl
#define SENT 0xFFFFFFFFFFFFFFFFull
#define SPIN_ROUNDS 200000

__device__ __forceinline__ float sigm_(float x){ return 1.0f/(1.0f + __expf(-x)); }
__device__ __forceinline__ float tanh_(float x){
  float ax = fabsf(x);
  float e  = __expf(-2.0f*ax);
  float r  = (1.0f - e)/(1.0f + e);
  return x < 0.0f ? -r : r;
}
__device__ __forceinline__ int imin_(int a,int b){ return a<b?a:b; }

// ================= K0: prep (QM, CB, W1T) =================
__global__ __launch_bounds__(512) void k0_prep(
    const float* __restrict__ q, const float* __restrict__ m,
    const float* __restrict__ W1, const float* __restrict__ b1,
    float* __restrict__ QM, float* __restrict__ CBo, f16* __restrict__ W1T)
{
  int tid = threadIdx.x;
  if (tid < 160){
    int k = tid >> 4, h = tid & 15;
    float acc = 0.f;
    for (int d = 0; d < 300; ++d)
      acc += q[k*300+d]*W1[(2100+d)*16+h] + m[k*300+d]*W1[(2400+d)*16+h];
    QM[tid] = acc;
  } else if (tid < 320){
    int b = (tid-160) >> 4, h = tid & 15;
    float acc = b1[h];
    for (int d = 0; d < 300; ++d)
      acc += m[b*300+d]*W1[(300+d)*16+h] + q[b*300+d]*W1[(600+d)*16+h];
    CBo[tid-160] = acc;
  }
  const int blkoff[5] = {0, 900, 1200, 1500, 1800};
  for (int i = tid; i < 25600; i += 512){
    int ii = i % 80; int r = i / 80;
    int dg = r % 4; r /= 4;
    int blk = r % 5; int h = r / 5;
    int d = dg*80 + ii;
    float v = 0.f;
    if (d < 300) v = W1[(blkoff[blk]+d)*16 + h];
    W1T[i] = (f16)v;
  }
}

// ================= Kpack: Whh -> MFMA A-fragment layout (f16) =================
__global__ __launch_bounds__(64) void k_pack(const float* __restrict__ Whh, f16* __restrict__ WhhP)
{
  int bid = blockIdx.x, l = threadIdx.x;
  int mt = bid / 10, kc = bid % 10;
  int gate = mt / 19, cb = mt % 19;
  int rr = l & 15, grp = l >> 4;
  int c = cb*16 + rr;
  int j = gate*300 + imin_(c, 299);
  f16x8 v;
  #pragma unroll
  for (int e = 0; e < 8; ++e){
    int d = kc*32 + grp*8 + e;
    float x = Whh[(size_t)imin_(d,299)*900 + j];
    v[e] = (f16)((d < 300 && c < 300) ? x : 0.f);
  }
  *(f16x8*)&WhhP[((size_t)bid*64 + l)*8] = v;
}

// ================= K1: attention gate -> G[b][t] (d_out[0:20480]) =================
__global__ __launch_bounds__(512) void k1_attn(
    const float* __restrict__ cs, const float* __restrict__ mI, const float* __restrict__ qI,
    const float* __restrict__ mask, const float* __restrict__ Wb,
    const float* __restrict__ W2, const float* __restrict__ b2,
    const float* __restrict__ QMg, const float* __restrict__ CBg, const f16* __restrict__ W1Tg,
    float* __restrict__ Gout)
{
  __shared__ __align__(16) float q_s[3000];
  __shared__ __align__(16) float m_s[3000];
  __shared__ float Wb_s[3000];
  __shared__ float QM_s[160], CB_s[160], W2_s[16];
  __shared__ __align__(16) f16 W1T_s[25600];
  __shared__ float cwb_s[8][10][10];
  int tid = threadIdx.x;
  for (int i = tid; i < 3000; i += 512){ q_s[i] = qI[i]; m_s[i] = mI[i]; Wb_s[i] = Wb[i]; }
  for (int i = tid; i < 160; i += 512){ QM_s[i] = QMg[i]; CB_s[i] = CBg[i]; }
  if (tid < 16) W2_s[tid] = W2[tid];
  for (int i = tid; i < 25600; i += 512) W1T_s[i] = W1Tg[i];
  __syncthreads();

  int w = tid >> 6, l = tid & 63, dg = l >> 4, lo = l & 15;
  int t = blockIdx.x*8 + w;
  float a[10], cwb[10];
  #pragma unroll
  for (int b = 0; b < 10; ++b){ a[b] = 0.f; cwb[b] = 0.f; }

  for (int i = 0; i < 10; ++i){
    int d0 = dg*80 + i*8;
    const int wbase = lo*1600 + dg*80 + i*8;
    f16x8 wf0 = *(const f16x8*)&W1T_s[wbase + 0*320];
    f16x8 wf1 = *(const f16x8*)&W1T_s[wbase + 1*320];
    f16x8 wf2 = *(const f16x8*)&W1T_s[wbase + 2*320];
    f16x8 wf3 = *(const f16x8*)&W1T_s[wbase + 3*320];
    f16x8 wf4 = *(const f16x8*)&W1T_s[wbase + 4*320];
    int dc0 = imin_(d0, 296), dc1 = imin_(d0 + 4, 296);
    #pragma unroll
    for (int b = 0; b < 10; ++b){
      const float* csb = cs + ((size_t)t*10 + b)*300;
      float4 c0 = *(const float4*)(csb + dc0);
      float4 c1 = *(const float4*)(csb + dc1);
      float4 q0 = *(const float4*)(q_s + b*300 + dc0);
      float4 q1 = *(const float4*)(q_s + b*300 + dc1);
      float4 m0 = *(const float4*)(m_s + b*300 + dc0);
      float4 m1 = *(const float4*)(m_s + b*300 + dc1);
      float cv[8] = {c0.x,c0.y,c0.z,c0.w,c1.x,c1.y,c1.z,c1.w};
      float qv[8] = {q0.x,q0.y,q0.z,q0.w,q1.x,q1.y,q1.z,q1.w};
      float mv[8] = {m0.x,m0.y,m0.z,m0.w,m1.x,m1.y,m1.z,m1.w};
      #pragma unroll
      for (int e = 0; e < 8; ++e){
        int d = d0 + e;
        float cvv = cv[e];
        a[b] += cvv*(float)wf0[e] + (cvv*qv[e])*(float)wf1[e] + (cvv*mv[e])*(float)wf2[e]
              + fabsf(cvv - qv[e])*(float)wf3[e] + fabsf(cvv - mv[e])*(float)wf4[e];
        float wv = Wb_s[imin_(d, 299)*10 + imin_(lo, 9)];
        wv = (lo < 10 && d < 300) ? wv : 0.f;
        cwb[b] += cvv*wv;
      }
    }
  }
  #pragma unroll
  for (int b = 0; b < 10; ++b){
    float v = cwb[b];
    v += __shfl_xor(v, 16, 64);
    v += __shfl_xor(v, 32, 64);
    cwb[b] = v;
  }
  if (dg == 0 && lo < 10){
    #pragma unroll
    for (int b = 0; b < 10; ++b) cwb_s[w][b][lo] = cwb[b];
  }
  __asm__ volatile("s_waitcnt lgkmcnt(0)" ::: "memory");
  __builtin_amdgcn_sched_barrier(0);
  float b2v = b2[0];
  #pragma unroll
  for (int b = 0; b < 10; ++b){
    float cross = 0.f;
    #pragma unroll
    for (int k = 0; k < 10; ++k) cross += cwb_s[w][b][k]*QM_s[k*16 + lo];
    float v = a[b];
    v += __shfl_xor(v, 16, 64);
    v += __shfl_xor(v, 32, 64);
    v += CB_s[b*16 + lo] + cross;
    float tv = tanh_(v)*W2_s[lo];
    tv += __shfl_xor(tv, 1, 64);
    tv += __shfl_xor(tv, 2, 64);
    tv += __shfl_xor(tv, 4, 64);
    tv += __shfl_xor(tv, 8, 64);
    a[b] = sigm_(tv + b2v);
  }
  if (l == 0){
    #pragma unroll
    for (int b = 0; b < 10; ++b) Gout[b*2048 + t] = a[b]*mask[t*10 + b];
  }
}

// ================= K2: softmax over T per b: Gs[t][b] =================
__global__ __launch_bounds__(256) void k2_softmax(const float* __restrict__ G, float* __restrict__ Gs)
{
  int b = blockIdx.x, tid = threadIdx.x;
  __shared__ float red[4];
  float v[8];
  #pragma unroll
  for (int k = 0; k < 8; ++k) v[k] = G[b*2048 + tid + k*256];
  float mx = v[0];
  #pragma unroll
  for (int k = 1; k < 8; ++k) mx = fmaxf(mx, v[k]);
  #pragma unroll
  for (int off = 1; off < 64; off <<= 1) mx = fmaxf(mx, __shfl_xor(mx, off, 64));
  if ((tid & 63) == 0) red[tid >> 6] = mx;
  __syncthreads();
  mx = fmaxf(fmaxf(red[0], red[1]), fmaxf(red[2], red[3]));
  __syncthreads();
  float e[8], s = 0.f;
  #pragma unroll
  for (int k = 0; k < 8; ++k){ e[k] = __expf(v[k]-mx); s += e[k]; }
  #pragma unroll
  for (int off = 1; off < 64; off <<= 1) s += __shfl_xor(s, off, 64);
  if ((tid & 63) == 0) red[tid >> 6] = s;
  __syncthreads();
  s = red[0]+red[1]+red[2]+red[3];
  float inv = 1.0f / s;
  #pragma unroll
  for (int k = 0; k < 8; ++k) Gs[(tid + k*256)*10 + b] = e[k]*inv;
}

// ================= K3: gi[t] = seq[t] @ Wih + bih (+bhh folded for r,z) =================
__global__ __launch_bounds__(256) void k3_gi(
    const float* __restrict__ cs, const float* __restrict__ Gs,
    const float* __restrict__ Wih, const float* __restrict__ bih, const float* __restrict__ bhh,
    f16* __restrict__ giP)
{
  int t = blockIdx.x, tid = threadIdx.x;
  __shared__ __align__(16) float sfT[300*16];
  for (int i = tid; i < 3000; i += 256){
    int d = i / 10, bcol = i % 10;
    int jj = d % 10;
    sfT[d*16 + bcol] = Gs[t*10 + jj] * cs[((size_t)t*10 + jj)*300 + bcol*30 + d/10];
  }
  __syncthreads();
  float acc[4][10];
  #pragma unroll
  for (int jp = 0; jp < 4; ++jp)
    #pragma unroll
    for (int b = 0; b < 10; ++b) acc[jp][b] = 0.f;
  for (int d = 0; d < 300; ++d){
    float4 s0 = *(const float4*)&sfT[d*16 + 0];
    float4 s1 = *(const float4*)&sfT[d*16 + 4];
    float4 s2 = *(const float4*)&sfT[d*16 + 8];
    float sb[10] = {s0.x,s0.y,s0.z,s0.w, s1.x,s1.y,s1.z,s1.w, s2.x,s2.y};
    #pragma unroll
    for (int jp = 0; jp < 4; ++jp){
      int j = jp*256 + tid;
      float wv = Wih[(size_t)d*900 + imin_(j, 899)];
      wv = (j < 900) ? wv : 0.f;
      #pragma unroll
      for (int b = 0; b < 10; ++b) acc[jp][b] += wv * sb[b];
    }
  }
  #pragma unroll
  for (int jp = 0; jp < 4; ++jp){
    int j = jp*256 + tid;
    if (j < 900){
      int gate = j / 300, c = j - gate*300;
      int cb = c >> 4, rr = c & 15;
      int mt = gate*19 + cb, g = rr >> 2, er = rr & 3;
      float bias = bih[j] + (j < 600 ? bhh[j] : 0.f);
      size_t base = ((size_t)t*57 + mt)*256;
      #pragma unroll
      for (int b = 0; b < 10; ++b)
        giP[base + (size_t)(((g<<4)|b)*4 + er)] = (f16)(acc[jp][b] + bias);
    }
  }
}

// ================= K4 v5: 19 WGs x 1 wave, sentinel exchange (no flags) =================
// h_s lives in parity s&3; slot for 4-col group cg = c/4 and batch bl is
// hx[par*HPAR + cg*16 + bl] (u64 = 4 f16). Slots pre-filled with SENT
// (f16 NaN pattern unreachable from (f16)(finite)). Consumers poll data
// slots directly until != SENT -> publish->observe is ~1.5 MALL RTTs.
// Re-sentinel: at step t each producer refills its slots in parity (t+2)&3
// (holds dead h_{t-2} by the skew invariant); one s_waitcnt vmcnt(0) before
// publish makes fills causally visible before the next h (wait is on stores
// issued a full step earlier -> free).
#define PIN_V(x) asm volatile("" : "+v"(x))

__global__ __launch_bounds__(64, 1) void k4_mesh(
    const f16* __restrict__ WhhP, const f16* __restrict__ giP,
    const float* __restrict__ mI, const float* __restrict__ bhh,
    unsigned long long* hx, float* __restrict__ hout)
{
  const int cb = blockIdx.x, l = threadIdx.x;
  const int bl = l & 15, grp = l >> 4;
  const int c0 = cb*16 + grp*4;          // this lane's output rows (as producer)
  const bool wv = (c0 < 300) && (bl < 10);
  const int pslot = (cb*4 + grp)*16 + bl; // publish slot index

  // resident A fragments: 3 gates x 10 kc (120 VGPRs), pinned
  f16x8 areg[3][10];
  #pragma unroll
  for (int gate = 0; gate < 3; ++gate){
    const int mt = gate*19 + cb;
    #pragma unroll
    for (int kc = 0; kc < 10; ++kc)
      areg[gate][kc] = *(const f16x8*)&WhhP[((size_t)(mt*10+kc)*64 + l)*8];
  }
  #pragma unroll
  for (int gate = 0; gate < 3; ++gate)
    #pragma unroll
    for (int kc = 0; kc < 10; ++kc)
      PIN_V(areg[gate][kc]);

  // consumer slot validity: slot_s for s = kc*2+j is ((kc*8+grp*2+j)*16 + bl)
  bool need[20];
  #pragma unroll
  for (int s = 0; s < 20; ++s){
    int cg = (s >> 1)*8 + grp*2 + (s & 1);
    need[s] = (cg < 75) && (bl < 10);
  }

  // h0 master (f32) + n-gate bias
  float hreg[4], bhhN[4];
  #pragma unroll
  for (int rg = 0; rg < 4; ++rg){
    int c = imin_(c0 + rg, 299);
    hreg[rg] = wv ? mI[bl*300 + c] : 0.f;
    bhhN[rg] = (c0 + rg < 300) ? bhh[600 + c] : 0.f;
  }
  // publish h0 into parity 0 (rest of buffer is sentinel from memset)
  if (wv){
    union { f16 h4[4]; unsigned long long u; } pk;
    #pragma unroll
    for (int rg = 0; rg < 4; ++rg) pk.h4[rg] = (f16)hreg[rg];
    __hip_atomic_store(&hx[pslot], pk.u, __ATOMIC_RELAXED, __HIP_MEMORY_SCOPE_AGENT);
  }

  for (int t = 0; t < 2048; ++t){
    // re-sentinel own slot in parity (t+2)&3 (holds dead h_{t-2})
    if (wv)
      __hip_atomic_store(&hx[(size_t)((t+2)&3)*HPAR + pslot], SENT,
                         __ATOMIC_RELAXED, __HIP_MEMORY_SCOPE_AGENT);

    // gi for this step — independent of h, issue before the exchange
    f16x4 gv[3];
    const f16* gp = giP + (size_t)t*14592;
    #pragma unroll
    for (int gate = 0; gate < 3; ++gate)
      gv[gate] = *(const f16x4*)&gp[(size_t)((gate*19+cb)*64 + l)*4];

    // poll data slots of parity t&3 until all fresh
    const unsigned long long* hb = hx + (size_t)(t & 3)*HPAR;
    unsigned long long v[20];
    #pragma unroll
    for (int s = 0; s < 20; ++s) v[s] = need[s] ? SENT : 0ull;
    int rounds = 0;
    bool all = false;
    while (!all){
      all = true;
      #pragma unroll
      for (int s = 0; s < 20; ++s){
        if (need[s] && v[s] == SENT){
          int cg = (s >> 1)*8 + grp*2 + (s & 1);
          v[s] = __hip_atomic_load(&hb[cg*16 + bl], __ATOMIC_RELAXED, __HIP_MEMORY_SCOPE_AGENT);
        }
      }
      #pragma unroll
      for (int s = 0; s < 20; ++s) all = all && (!need[s] || v[s] != SENT);
      if (++rounds > SPIN_ROUNDS) break;   // fail-fast: wrong answer, no hang
    }
    __builtin_amdgcn_sched_barrier(0);

    // assemble B fragments
    f16x8 bf[10];
    #pragma unroll
    for (int kc = 0; kc < 10; ++kc){
      union { unsigned long long u[2]; f16x8 w; } cv;
      cv.u[0] = v[kc*2+0];
      cv.u[1] = v[kc*2+1];
      bf[kc] = cv.w;
    }

    // 30 MFMA, 3 independent chains
    f32x4 a0 = {0.f,0.f,0.f,0.f}, a1 = {0.f,0.f,0.f,0.f}, a2 = {0.f,0.f,0.f,0.f};
    #pragma unroll
    for (int kc = 0; kc < 10; ++kc){
      a0 = __builtin_amdgcn_mfma_f32_16x16x32_f16(areg[0][kc], bf[kc], a0, 0, 0, 0);
      a1 = __builtin_amdgcn_mfma_f32_16x16x32_f16(areg[1][kc], bf[kc], a1, 0, 0, 0);
      a2 = __builtin_amdgcn_mfma_f32_16x16x32_f16(areg[2][kc], bf[kc], a2, 0, 0, 0);
    }

    // in-lane combine + publish h_{t+1} into parity (t+1)&3
    asm volatile("s_waitcnt vmcnt(0)" ::: "memory");   // fills (issued ~1 step ago) acked
    if (wv){
      union { f16 h4[4]; unsigned long long u; } pk;
      #pragma unroll
      for (int rg = 0; rg < 4; ++rg){
        float r  = sigm_(a0[rg] + (float)gv[0][rg]);
        float z  = sigm_(a1[rg] + (float)gv[1][rg]);
        float n  = tanh_((float)gv[2][rg] + r*(a2[rg] + bhhN[rg]));
        float hn = (1.f - z)*n + z*hreg[rg];
        hreg[rg] = hn;
        pk.h4[rg] = (f16)hn;
      }
      __hip_atomic_store(&hx[(size_t)((t+1)&3)*HPAR + pslot], pk.u,
                         __ATOMIC_RELAXED, __HIP_MEMORY_SCOPE_AGENT);
    }
  }

  // final h (exact f32 master)
  if (wv){
    #pragma unroll
    for (int rg = 0; rg < 4; ++rg)
      hout[bl*300 + c0 + rg] = hreg[rg];
  }
}

// ================= launch =================
extern "C" void kernel_launch(void* const* d_in, const int* in_sizes, int n_in,
                              void* d_out, int out_size, void* d_ws, size_t ws_size,
                              hipStream_t stream)
{
  const float* cs   = (const float*)d_in[0];
  const float* m    = (const float*)d_in[1];
  const float* q    = (const float*)d_in[2];
  const float* mask = (const float*)d_in[3];
  const float* Wb   = (const float*)d_in[4];
  const float* W1   = (const float*)d_in[5];
  const float* b1   = (const float*)d_in[6];
  const float* W2   = (const float*)d_in[7];
  const float* b2   = (const float*)d_in[8];
  const float* Wih  = (const float*)d_in[9];
  const float* Whh  = (const float*)d_in[10];
  const float* bih  = (const float*)d_in[11];
  const float* bhh  = (const float*)d_in[12];
  float* out = (float*)d_out;
  char* ws = (char*)d_ws;
  float* Gs   = (float*)(ws + WS_GS);
  float* QM   = (float*)(ws + WS_QM);
  float* CB   = (float*)(ws + WS_CB);
  f16*   W1T  = (f16*)(ws + WS_W1T);
  f16*   WhhP = (f16*)(ws + WS_WHHP);
  f16*   giP  = (f16*)(ws + WS_GIP);
  unsigned long long* hx = (unsigned long long*)(ws + WS_HX);

  k0_prep<<<dim3(1), dim3(512), 0, stream>>>(q, m, W1, b1, QM, CB, W1T);
  k_pack<<<dim3(570), dim3(64), 0, stream>>>(Whh, WhhP);
  k1_attn<<<dim3(256), dim3(512), 0, stream>>>(cs, m, q, mask, Wb, W2, b2, QM, CB, W1T, out);
  k2_softmax<<<dim3(10), dim3(256), 0, stream>>>(out, Gs);
  k3_gi<<<dim3(2048), dim3(256), 0, stream>>>(cs, Gs, Wih, bih, bhh, giP);
  // W1T region dead after k1 -> sentinel-fill the 4-parity exchange buffer
  hipMemsetAsync(ws + WS_HX, 0xFF, 4*HPAR*8, stream);
  k4_mesh<<<dim3(19), dim3(64), 0, stream>>>(WhhP, giP, m, bhh, hx, out + 20480);
}